// Round 8
// baseline (185.020 us; speedup 1.0000x reference)
//
#include <hip/hip_runtime.h>

// PatchMatch brute-force NN on MI355X.
// s,t (4,16,64,64) fp32; descriptor = 3x3 replicate-padded patch, K=144 (pad 160).
// d2(i,j) = qn_i - 2*cross(i,j) + pn_j; argmin_j (ties -> smallest j).
// Outputs (flat, ALL FLOAT32): nnf (4,2,64,64) then nnd (4,1,64,64).
//
// R8 vs R7 (158us total; mfma 94us, MfmaUtil 27%, VGPR=88 => compiler was
// REMATERIALIZING A-frag loads (80 VGPR of A can't fit in 88) -> 51MB fetch;
// LDS pipe ~= MFMA pipe, barrier-serialized):
//  - NO LDS in the GEMM kernel. Descriptors stored K-major [n][kk][pix][8];
//    A- and B-frags load straight from global (L2) fully coalesced.
//  - Wave covers 64 i (A hi/lo resident, 160 VGPR) streaming 16-j tiles:
//    B traffic 4x lower than R7-equivalent, ~19us of L2 traffic under the
//    31us MFMA floor. No barriers at all.
//  - __launch_bounds__(256,2): 256-VGPR budget so the allocator keeps A
//    resident instead of rematerializing.

#define N_  4
#define C_  16
#define H_  64
#define W_  64
#define HW_ 4096
#define K_  160              // 144 real + 16 zero-pad; 20 chunks of 8
#define SPLITS_M 8           // j-splits; 512 j per split, 32 tiles of 16

#define SPLITS_V 4           // fallback j-splits
#define TILES_PER_SPLIT_V 4

typedef _Float16 f16;
typedef _Float16 f16x8 __attribute__((ext_vector_type(8)));
typedef float    f32x4 __attribute__((ext_vector_type(4)));

__device__ __forceinline__ int iclamp(int v, int lo, int hi) {
    return v < lo ? lo : (v > hi ? hi : v);
}

// ---------------------------------------------------------------------------
// Kernel 1: build K-major fp16 hi/lo descriptors AND squared norms.
// Layout: D[(n*20 + kk)*4096 + pix][8], kk = k/8, k = d*16 + c (d = dy*3+dx).
// kk 18,19 are zero padding. grid (64, N_, 2): z=0 -> t->Ph/Pl+pn, z=1 -> s.
// 4 threads per pix, 5 kk-chunks each.
// ---------------------------------------------------------------------------
__global__ __launch_bounds__(256)
void build_desc_norms_kernel(const float* __restrict__ s,
                             const float* __restrict__ t,
                             f16* __restrict__ Qh, f16* __restrict__ Ql,
                             f16* __restrict__ Ph, f16* __restrict__ Pl,
                             float* __restrict__ pn,
                             float* __restrict__ qn) {
    const int pix = blockIdx.x * 64 + (threadIdx.x >> 2);
    const int n   = blockIdx.y;
    const int src = blockIdx.z;                 // 0: t, 1: s
    const int y = pix >> 6, x = pix & 63;
    const float* img = (src ? s : t) + n * (C_ * HW_);
    f16* Dh = (src ? Qh : Ph);
    f16* Dl = (src ? Ql : Pl);
    float nacc = 0.f;
    #pragma unroll
    for (int q = 0; q < 5; ++q) {
        const int kk = (threadIdx.x & 3) * 5 + q;    // 0..19
        f16x8 hv, lv;
        if (kk < 18) {
            const int d  = kk >> 1;                  // 0..8
            const int c0 = (kk & 1) * 8;
            const int dy = (d >= 6) ? 2 : (d >= 3 ? 1 : 0);
            const int dx = d - dy * 3;
            const int ys = iclamp(y + dy - 1, 0, H_ - 1);
            const int xs = iclamp(x + dx - 1, 0, W_ - 1);
            const float* p0 = img + c0 * HW_ + ys * W_ + xs;
            #pragma unroll
            for (int cc = 0; cc < 8; ++cc) {
                const float v = p0[cc * HW_];
                const f16 h = (f16)v;
                hv[cc] = h;
                lv[cc] = (f16)(v - (float)h);
                nacc += v * v;
            }
        } else {
            #pragma unroll
            for (int cc = 0; cc < 8; ++cc) { hv[cc] = (f16)0.f; lv[cc] = (f16)0.f; }
        }
        const size_t off = ((size_t)(n * 20 + kk) * HW_ + pix) * 8;
        *(f16x8*)&Dh[off] = hv;
        *(f16x8*)&Dl[off] = lv;
    }
    nacc += __shfl_xor(nacc, 1, 64);
    nacc += __shfl_xor(nacc, 2, 64);
    if ((threadIdx.x & 3) == 0)
        (src ? qn : pn)[n * HW_ + pix] = nacc;
}

// ---------------------------------------------------------------------------
// Kernel 2: MFMA GEMM + fused argmin, NO LDS / NO barriers.
// Block 256 thr = 4 waves; wave covers 64 i (4 x 16), block 256 i.
// j streamed in 16-wide tiles (32 tiles per split). All frags from global
// K-major layout: lane(m,quad) reads [(n*20 + kc*4+quad)*4096 + row]*8 —
// 16 consecutive rows per quad = 256 B contiguous (coalesced dwordx4).
// mfma_f32_16x16x32_f16: C col = lane&15 (=m -> j), row = quad*4+reg.
// ---------------------------------------------------------------------------
__global__ __launch_bounds__(256, 2)
void mfma_nn_kernel(const f16* __restrict__ Qh, const f16* __restrict__ Ql,
                    const f16* __restrict__ Ph, const f16* __restrict__ Pl,
                    const float* __restrict__ pn_g,
                    unsigned long long* __restrict__ partial) {
    const int iblk = blockIdx.x, n = blockIdx.y, split = blockIdx.z;
    const int tid  = threadIdx.x;
    const int wave = tid >> 6, lane = tid & 63;
    const int m = lane & 15, quad = lane >> 4;

    const int irow0 = iblk * 256 + wave * 64;

    // ---- A fragments, resident for the whole kernel (160 VGPR) ----
    f16x8 Ah[4][5], Al[4][5];
    #pragma unroll
    for (int is = 0; is < 4; ++is)
        #pragma unroll
        for (int kc = 0; kc < 5; ++kc) {
            const size_t off = ((size_t)(n * 20 + kc * 4 + quad) * HW_ +
                                irow0 + is * 16 + m) * 8;
            Ah[is][kc] = *(const f16x8*)(Qh + off);
            Al[is][kc] = *(const f16x8*)(Ql + off);
        }

    float    bd[4][4];
    unsigned bj[4][4];
    #pragma unroll
    for (int is = 0; is < 4; ++is)
        #pragma unroll
        for (int rg = 0; rg < 4; ++rg) { bd[is][rg] = 3.0e38f; bj[is][rg] = 0u; }

    for (int jt = 0; jt < 32; ++jt) {
        const int j0 = split * 512 + jt * 16;
        const float pnv = pn_g[n * HW_ + j0 + m];   // this lane's j column

        f32x4 Cf[4];
        #pragma unroll
        for (int is = 0; is < 4; ++is) Cf[is] = (f32x4){0.f, 0.f, 0.f, 0.f};

        #pragma unroll
        for (int kc = 0; kc < 5; ++kc) {
            const size_t boff = ((size_t)(n * 20 + kc * 4 + quad) * HW_ +
                                 j0 + m) * 8;
            const f16x8 bh = *(const f16x8*)(Ph + boff);
            const f16x8 bl = *(const f16x8*)(Pl + boff);
            #pragma unroll
            for (int is = 0; is < 4; ++is) {
                Cf[is] = __builtin_amdgcn_mfma_f32_16x16x32_f16(
                    Ah[is][kc], bh, Cf[is], 0, 0, 0);
                Cf[is] = __builtin_amdgcn_mfma_f32_16x16x32_f16(
                    Al[is][kc], bh, Cf[is], 0, 0, 0);
                Cf[is] = __builtin_amdgcn_mfma_f32_16x16x32_f16(
                    Ah[is][kc], bl, Cf[is], 0, 0, 0);
            }
        }

        // epilogue: d' = pn - 2*cross (qn added in finalize); 1 candidate
        // per (is,rg) per tile — strict < keeps earliest j within a lane.
        #pragma unroll
        for (int is = 0; is < 4; ++is)
            #pragma unroll
            for (int rg = 0; rg < 4; ++rg) {
                const float d = fmaf(Cf[is][rg], -2.f, pnv);
                if (d < bd[is][rg]) {
                    bd[is][rg] = d;
                    bj[is][rg] = (unsigned)(j0 + m);
                }
            }
    }

    // ---- reduce across the 16 m-lanes (same quad = same i rows) ----
    #pragma unroll
    for (int is = 0; is < 4; ++is)
        #pragma unroll
        for (int rg = 0; rg < 4; ++rg) {
            float    d = bd[is][rg];
            unsigned j = bj[is][rg];
            #pragma unroll
            for (int off = 1; off < 16; off <<= 1) {
                const float    od = __shfl_xor(d, off, 64);
                const unsigned oj = __shfl_xor(j, off, 64);
                const bool take = (od < d) || (od == d && oj < j);
                d = take ? od : d;
                j = take ? oj : j;
            }
            if (m == 0) {
                const int i = irow0 + is * 16 + quad * 4 + rg;
                partial[(size_t)(split * N_ + n) * HW_ + i] =
                    ((unsigned long long)j << 32) |
                    (unsigned long long)__float_as_uint(d);
            }
        }
}

// ---------------------------------------------------------------------------
// Kernel 3: reduce splits, add qn, decode, write outputs (float32)
// ---------------------------------------------------------------------------
__global__ __launch_bounds__(256)
void finalize_mfma_kernel(const unsigned long long* __restrict__ partial,
                          const float* __restrict__ qn_g,
                          float* __restrict__ out) {
    const int id  = blockIdx.x * 256 + threadIdx.x;   // 0..16383
    const int n   = id >> 12;
    const int pix = id & 4095;
    float    bd = 3.0e38f;
    unsigned bj = 0u;
    #pragma unroll
    for (int sp = 0; sp < SPLITS_M; ++sp) {
        const unsigned long long v = partial[(size_t)(sp * N_ + n) * HW_ + pix];
        const float    d = __uint_as_float((unsigned)(v & 0xffffffffull));
        const unsigned j = (unsigned)(v >> 32);
        const bool take = (d < bd) || (d == bd && j < bj);
        bd = take ? d : bd;
        bj = take ? j : bj;
    }
    out[n * 2 * HW_ + pix]            = (float)(bj >> 6);          // idy
    out[n * 2 * HW_ + HW_ + pix]      = (float)(bj & 63);          // idx_x
    out[N_ * 2 * HW_ + n * HW_ + pix] = bd + qn_g[n * HW_ + pix];  // nnd
}

// ===========================================================================
// Fallback path (fp32 vector, R4 structure) + helpers
// ===========================================================================
__global__ __launch_bounds__(256)
void prep_norms_kernel(const float* __restrict__ s,
                       const float* __restrict__ t,
                       float* __restrict__ pn,
                       float* __restrict__ qn) {
    const int gid   = blockIdx.x * 256 + threadIdx.x;
    const int which = gid >> 14;
    const int id    = gid & 16383;
    const int n     = id >> 12;
    const int pix   = id & 4095;
    const int y = pix >> 6, x = pix & 63;
    const float* base = (which ? s : t) + n * (C_ * HW_);
    float acc = 0.f;
    for (int c = 0; c < C_; ++c) {
        const float* bc = base + c * HW_;
        #pragma unroll
        for (int dy = 0; dy < 3; ++dy) {
            const float* br = bc + iclamp(y + dy - 1, 0, H_ - 1) * W_;
            #pragma unroll
            for (int dx = 0; dx < 3; ++dx) {
                float v = br[iclamp(x + dx - 1, 0, W_ - 1)];
                acc += v * v;
            }
        }
    }
    (which ? qn : pn)[id] = acc;
}

__global__ __launch_bounds__(256)
void patchmatch_main_kernel(const float* __restrict__ s,
                            const float* __restrict__ t,
                            const float* __restrict__ pn_g,
                            const float* __restrict__ qn_g,
                            unsigned long long* __restrict__ partial) {
    const int yq    = blockIdx.x;
    const int n     = blockIdx.y;
    const int split = blockIdx.z;
    const int tid  = threadIdx.x;
    const int tx   = tid & 15;
    const int ty   = tid >> 4;
    const int i0   = ty * 4;
    const int jrow = tx >> 2;
    const int jx0  = (tx & 3) * 16;

    __shared__ float qS[C_][3][68];
    __shared__ float tS[C_][6][68];
    __shared__ float qnS[W_];

    const float* sb = s + n * (C_ * HW_);
    const float* tb = t + n * (C_ * HW_);

    #pragma unroll
    for (int k = 0; k < 3; ++k) {
        const int id = tid + k * 256;
        const int sg = id & 15;
        const int c  = (id >> 4) & 15;
        const int r  = id >> 8;
        const int gr = iclamp(yq + r - 1, 0, H_ - 1);
        const float4 v = *(const float4*)&sb[c * HW_ + gr * W_ + sg * 4];
        float* dst = &qS[c][r][1 + sg * 4];
        dst[0] = v.x; dst[1] = v.y; dst[2] = v.z; dst[3] = v.w;
    }
    if (tid < 48) {
        const int c  = tid & 15;
        const int r  = tid >> 4;
        const int gr = iclamp(yq + r - 1, 0, H_ - 1);
        qS[c][r][0]  = sb[c * HW_ + gr * W_];
        qS[c][r][65] = sb[c * HW_ + gr * W_ + 63];
    }
    if (tid < W_) qnS[tid] = qn_g[n * HW_ + yq * W_ + tid];

    unsigned long long best[4] = {~0ull, ~0ull, ~0ull, ~0ull};

    for (int ytl = 0; ytl < TILES_PER_SPLIT_V; ++ytl) {
        const int yt = split * TILES_PER_SPLIT_V + ytl;
        __syncthreads();
        #pragma unroll
        for (int k = 0; k < 6; ++k) {
            const int id = tid + k * 256;
            const int sg = id & 15;
            const int c  = (id >> 4) & 15;
            const int r  = id >> 8;
            const int gr = iclamp(4 * yt + r - 1, 0, H_ - 1);
            const float4 v = *(const float4*)&tb[c * HW_ + gr * W_ + sg * 4];
            float* dst = &tS[c][r][1 + sg * 4];
            dst[0] = v.x; dst[1] = v.y; dst[2] = v.z; dst[3] = v.w;
        }
        if (tid < 96) {
            const int c  = tid & 15;
            const int r  = tid >> 4;
            const int gr = iclamp(4 * yt + r - 1, 0, H_ - 1);
            tS[c][r][0]  = tb[c * HW_ + gr * W_];
            tS[c][r][65] = tb[c * HW_ + gr * W_ + 63];
        }
        __syncthreads();

        float acc[4][16];
        #pragma unroll
        for (int a = 0; a < 4; ++a)
            #pragma unroll
            for (int b = 0; b < 16; ++b) acc[a][b] = 0.f;

        for (int c = 0; c < C_; ++c) {
            #pragma unroll
            for (int dy = 0; dy < 3; ++dy) {
                float qv[6], tv[18];
                *(float4*)&qv[0] = *(const float4*)&qS[c][dy][i0];
                *(float2*)&qv[4] = *(const float2*)&qS[c][dy][i0 + 4];
                const float* trow = &tS[c][jrow + dy][jx0];
                *(float4*)&tv[0]  = *(const float4*)&trow[0];
                *(float4*)&tv[4]  = *(const float4*)&trow[4];
                *(float4*)&tv[8]  = *(const float4*)&trow[8];
                *(float4*)&tv[12] = *(const float4*)&trow[12];
                *(float2*)&tv[16] = *(const float2*)&trow[16];
                #pragma unroll
                for (int dx = 0; dx < 3; ++dx)
                    #pragma unroll
                    for (int a = 0; a < 4; ++a)
                        #pragma unroll
                        for (int b = 0; b < 16; ++b)
                            acc[a][b] += qv[a + dx] * tv[b + dx];
            }
        }

        const int jbase = yt * 256 + jrow * W_ + jx0;
        float pnv[16];
        const float* png = &pn_g[n * HW_ + jbase];
        *(float4*)&pnv[0]  = *(const float4*)&png[0];
        *(float4*)&pnv[4]  = *(const float4*)&png[4];
        *(float4*)&pnv[8]  = *(const float4*)&png[8];
        *(float4*)&pnv[12] = *(const float4*)&png[12];
        #pragma unroll
        for (int a = 0; a < 4; ++a) {
            const float qn = qnS[i0 + a];
            #pragma unroll
            for (int b = 0; b < 16; ++b) {
                const float d2 = qn + pnv[b] - 2.f * acc[a][b];
                unsigned long long cand =
                    ((unsigned long long)__float_as_uint(d2) << 32) |
                    (unsigned)(jbase + b);
                best[a] = cand < best[a] ? cand : best[a];
            }
        }
    }

    #pragma unroll
    for (int a = 0; a < 4; ++a) {
        unsigned long long v = best[a];
        #pragma unroll
        for (int mm = 8; mm >= 1; mm >>= 1) {
            unsigned long long o = __shfl_xor(v, mm, 64);
            v = o < v ? o : v;
        }
        best[a] = v;
    }
    if (tx == 0) {
        #pragma unroll
        for (int a = 0; a < 4; ++a)
            partial[((split * N_ + n) * HW_) + yq * W_ + i0 + a] = best[a];
    }
}

__global__ __launch_bounds__(256)
void finalize_kernel(const unsigned long long* __restrict__ partial,
                     float* __restrict__ out) {
    const int id  = blockIdx.x * 256 + threadIdx.x;
    const int n   = id >> 12;
    const int pix = id & 4095;
    unsigned long long best = ~0ull;
    #pragma unroll
    for (int sp = 0; sp < SPLITS_V; ++sp) {
        unsigned long long v = partial[(sp * N_ + n) * HW_ + pix];
        best = v < best ? v : best;
    }
    const unsigned j = (unsigned)(best & 0xffffffffu);
    const float d2 = __uint_as_float((unsigned)(best >> 32));
    out[n * 2 * HW_ + pix]            = (float)(j >> 6);
    out[n * 2 * HW_ + HW_ + pix]      = (float)(j & 63);
    out[N_ * 2 * HW_ + n * HW_ + pix] = d2;
}

__global__ __launch_bounds__(256)
void patchmatch_mono_kernel(const float* __restrict__ s,
                            const float* __restrict__ t,
                            float* __restrict__ out) {
    const int yq  = blockIdx.x;
    const int n   = blockIdx.y;
    const int tid = threadIdx.x;
    const int tx  = tid & 15;
    const int ty  = tid >> 4;
    const int i0  = ty * 4;
    const int jrow = tx >> 3;
    const int jx0  = (tx & 7) * 8;

    __shared__ float qS[C_][3][68];
    __shared__ float tS[C_][4][68];
    __shared__ float pnS[HW_];
    __shared__ float qnS[W_];

    const float* sb = s + n * (C_ * HW_);
    const float* tb = t + n * (C_ * HW_);

    for (int jj = tid; jj < HW_; jj += 256) {
        const int y = jj >> 6, x = jj & 63;
        float acc = 0.f;
        for (int c = 0; c < C_; ++c) {
            const float* tc = tb + c * HW_;
            #pragma unroll
            for (int dy = 0; dy < 3; ++dy) {
                const float* tr = tc + iclamp(y + dy - 1, 0, H_ - 1) * W_;
                #pragma unroll
                for (int dx = 0; dx < 3; ++dx) {
                    float v = tr[iclamp(x + dx - 1, 0, W_ - 1)];
                    acc += v * v;
                }
            }
        }
        pnS[jj] = acc;
    }
    for (int idx = tid; idx < C_ * 3 * 66; idx += 256) {
        const int c   = idx / (3 * 66);
        const int rem = idx - c * (3 * 66);
        const int rr  = rem / 66;
        const int xi  = rem - rr * 66;
        qS[c][rr][xi] = sb[c * HW_ + iclamp(yq + rr - 1, 0, H_ - 1) * W_ +
                           iclamp(xi - 1, 0, W_ - 1)];
    }
    __syncthreads();
    if (tid < W_) {
        float acc = 0.f;
        for (int c = 0; c < C_; ++c)
            #pragma unroll
            for (int dy = 0; dy < 3; ++dy)
                #pragma unroll
                for (int dx = 0; dx < 3; ++dx) {
                    float v = qS[c][dy][tid + dx];
                    acc += v * v;
                }
        qnS[tid] = acc;
    }

    unsigned long long best[4] = {~0ull, ~0ull, ~0ull, ~0ull};
    for (int yt = 0; yt < 32; ++yt) {
        __syncthreads();
        for (int idx = tid; idx < C_ * 4 * 66; idx += 256) {
            const int c   = idx / (4 * 66);
            const int rem = idx - c * (4 * 66);
            const int rr  = rem / 66;
            const int xi  = rem - rr * 66;
            tS[c][rr][xi] = tb[c * HW_ + iclamp(2 * yt + rr - 1, 0, H_ - 1) * W_ +
                               iclamp(xi - 1, 0, W_ - 1)];
        }
        __syncthreads();

        float acc[4][8];
        #pragma unroll
        for (int a = 0; a < 4; ++a)
            #pragma unroll
            for (int b = 0; b < 8; ++b) acc[a][b] = 0.f;

        for (int c = 0; c < C_; ++c) {
            #pragma unroll
            for (int dy = 0; dy < 3; ++dy) {
                float qv[8], tv[12];
                *(float4*)&qv[0] = *(const float4*)&qS[c][dy][i0];
                *(float4*)&qv[4] = *(const float4*)&qS[c][dy][i0 + 4];
                const float* trow = &tS[c][jrow + dy][jx0];
                *(float4*)&tv[0] = *(const float4*)&trow[0];
                *(float4*)&tv[4] = *(const float4*)&trow[4];
                *(float4*)&tv[8] = *(const float4*)&trow[8];
                #pragma unroll
                for (int dx = 0; dx < 3; ++dx)
                    #pragma unroll
                    for (int a = 0; a < 4; ++a)
                        #pragma unroll
                        for (int b = 0; b < 8; ++b)
                            acc[a][b] += qv[a + dx] * tv[b + dx];
            }
        }
        const int rbase = (2 * yt + jrow) * W_ + jx0;
        #pragma unroll
        for (int a = 0; a < 4; ++a) {
            const float qn = qnS[i0 + a];
            #pragma unroll
            for (int b = 0; b < 8; ++b) {
                const int j = rbase + b;
                const float d2 = qn + pnS[j] - 2.f * acc[a][b];
                unsigned long long cand =
                    ((unsigned long long)__float_as_uint(d2) << 32) | (unsigned)j;
                best[a] = cand < best[a] ? cand : best[a];
            }
        }
    }
    #pragma unroll
    for (int a = 0; a < 4; ++a) {
        unsigned long long v = best[a];
        #pragma unroll
        for (int mm = 8; mm >= 1; mm >>= 1) {
            unsigned long long o = __shfl_xor(v, mm, 64);
            v = o < v ? o : v;
        }
        best[a] = v;
    }
    if (tx == 0) {
        #pragma unroll
        for (int a = 0; a < 4; ++a) {
            const int x = i0 + a;
            const unsigned j = (unsigned)(best[a] & 0xffffffffu);
            const float d2 = __uint_as_float((unsigned)(best[a] >> 32));
            const int pix = yq * W_ + x;
            out[n * 2 * HW_ + pix]            = (float)(j >> 6);
            out[n * 2 * HW_ + HW_ + pix]      = (float)(j & 63);
            out[N_ * 2 * HW_ + n * HW_ + pix] = d2;
        }
    }
}

// ===========================================================================
extern "C" void kernel_launch(void* const* d_in, const int* in_sizes, int n_in,
                              void* d_out, int out_size, void* d_ws, size_t ws_size,
                              hipStream_t stream) {
    const float* s = (const float*)d_in[0];
    const float* t = (const float*)d_in[1];
    float* out = (float*)d_out;

    // MFMA ws layout:
    //   pn [4][4096] f32 | qn [4][4096] f32 | partial [8][4][4096] u64 |
    //   Qh | Ql | Ph | Pl   each K-major [4][20][4096][8] f16 (5.24 MB)
    const size_t norm_b  = (size_t)N_ * HW_ * 4;
    const size_t part_b  = (size_t)SPLITS_M * N_ * HW_ * 8;
    const size_t desc_b  = (size_t)N_ * HW_ * K_ * 2;
    const size_t need_m  = 2 * norm_b + part_b + 4 * desc_b;     // ~22 MB

    if (ws_size >= need_m) {
        char* w = (char*)d_ws;
        float* pn = (float*)w;                       w += norm_b;
        float* qn = (float*)w;                       w += norm_b;
        unsigned long long* partial = (unsigned long long*)w; w += part_b;
        f16* Qh = (f16*)w;  w += desc_b;
        f16* Ql = (f16*)w;  w += desc_b;
        f16* Ph = (f16*)w;  w += desc_b;
        f16* Pl = (f16*)w;

        build_desc_norms_kernel<<<dim3(64, N_, 2), 256, 0, stream>>>(
            s, t, Qh, Ql, Ph, Pl, pn, qn);
        mfma_nn_kernel<<<dim3(16, N_, SPLITS_M), 256, 0, stream>>>(
            Qh, Ql, Ph, Pl, pn, partial);
        finalize_mfma_kernel<<<64, 256, 0, stream>>>(partial, qn, out);
        return;
    }

    // Fallback: fp32 vector path
    const size_t need_v = 2 * norm_b + (size_t)SPLITS_V * N_ * HW_ * 8;
    if (ws_size >= need_v) {
        float* pn = (float*)d_ws;
        float* qn = pn + N_ * HW_;
        unsigned long long* partial =
            (unsigned long long*)((char*)d_ws + 2 * norm_b);
        prep_norms_kernel<<<128, 256, 0, stream>>>(s, t, pn, qn);
        dim3 grid(H_, N_, SPLITS_V);
        patchmatch_main_kernel<<<grid, 256, 0, stream>>>(s, t, pn, qn, partial);
        finalize_kernel<<<64, 256, 0, stream>>>(partial, out);
        return;
    }

    dim3 grid(H_, N_);
    patchmatch_mono_kernel<<<grid, 256, 0, stream>>>(s, t, out);
}

// Round 9
// 184.479 us; speedup vs baseline: 1.0029x; 1.0029x over previous
//
#include <hip/hip_runtime.h>

// PatchMatch brute-force NN on MI355X.
// s,t (4,16,64,64) fp32; descriptor = 3x3 replicate-padded patch, K=144 (pad 160).
// d2(i,j) = qn_i - 2*cross(i,j) + pn_j; argmin_j (ties -> smallest j).
// Outputs (flat, ALL FLOAT32): nnf (4,2,64,64) then nnd (4,1,64,64).
//
// R9 vs R8 (mfma 121us, VGPR=120 => A-frags (160 VGPR) STILL rematerialized
// from L2 every jt tile ~ 2.6GB of L2 reads ~ 76us):
//  - A-fragments pinned with empty `asm volatile("" : "+v")` after the
//    one-time load: inline-asm results cannot be rematerialized, forcing
//    residence (~235 VGPR, fits 256 budget @ 2 waves/SIMD).
//  - everything else identical to R8 (no LDS, no barriers, K-major frags).

#define N_  4
#define C_  16
#define H_  64
#define W_  64
#define HW_ 4096
#define K_  160              // 144 real + 16 zero-pad; 20 chunks of 8
#define SPLITS_M 8           // j-splits; 512 j per split, 32 tiles of 16

#define SPLITS_V 4           // fallback j-splits
#define TILES_PER_SPLIT_V 4

typedef _Float16 f16;
typedef _Float16 f16x8 __attribute__((ext_vector_type(8)));
typedef float    f32x4 __attribute__((ext_vector_type(4)));

__device__ __forceinline__ int iclamp(int v, int lo, int hi) {
    return v < lo ? lo : (v > hi ? hi : v);
}

// ---------------------------------------------------------------------------
// Kernel 1: build K-major fp16 hi/lo descriptors AND squared norms.
// Layout: D[(n*20 + kk)*4096 + pix][8], kk = k/8, k = d*16 + c (d = dy*3+dx).
// kk 18,19 are zero padding. grid (64, N_, 2): z=0 -> t->Ph/Pl+pn, z=1 -> s.
// 4 threads per pix, 5 kk-chunks each.
// ---------------------------------------------------------------------------
__global__ __launch_bounds__(256)
void build_desc_norms_kernel(const float* __restrict__ s,
                             const float* __restrict__ t,
                             f16* __restrict__ Qh, f16* __restrict__ Ql,
                             f16* __restrict__ Ph, f16* __restrict__ Pl,
                             float* __restrict__ pn,
                             float* __restrict__ qn) {
    const int pix = blockIdx.x * 64 + (threadIdx.x >> 2);
    const int n   = blockIdx.y;
    const int src = blockIdx.z;                 // 0: t, 1: s
    const int y = pix >> 6, x = pix & 63;
    const float* img = (src ? s : t) + n * (C_ * HW_);
    f16* Dh = (src ? Qh : Ph);
    f16* Dl = (src ? Ql : Pl);
    float nacc = 0.f;
    #pragma unroll
    for (int q = 0; q < 5; ++q) {
        const int kk = (threadIdx.x & 3) * 5 + q;    // 0..19
        f16x8 hv, lv;
        if (kk < 18) {
            const int d  = kk >> 1;                  // 0..8
            const int c0 = (kk & 1) * 8;
            const int dy = (d >= 6) ? 2 : (d >= 3 ? 1 : 0);
            const int dx = d - dy * 3;
            const int ys = iclamp(y + dy - 1, 0, H_ - 1);
            const int xs = iclamp(x + dx - 1, 0, W_ - 1);
            const float* p0 = img + c0 * HW_ + ys * W_ + xs;
            #pragma unroll
            for (int cc = 0; cc < 8; ++cc) {
                const float v = p0[cc * HW_];
                const f16 h = (f16)v;
                hv[cc] = h;
                lv[cc] = (f16)(v - (float)h);
                nacc += v * v;
            }
        } else {
            #pragma unroll
            for (int cc = 0; cc < 8; ++cc) { hv[cc] = (f16)0.f; lv[cc] = (f16)0.f; }
        }
        const size_t off = ((size_t)(n * 20 + kk) * HW_ + pix) * 8;
        *(f16x8*)&Dh[off] = hv;
        *(f16x8*)&Dl[off] = lv;
    }
    nacc += __shfl_xor(nacc, 1, 64);
    nacc += __shfl_xor(nacc, 2, 64);
    if ((threadIdx.x & 3) == 0)
        (src ? qn : pn)[n * HW_ + pix] = nacc;
}

// ---------------------------------------------------------------------------
// Kernel 2: MFMA GEMM + fused argmin, NO LDS / NO barriers.
// Block 256 thr = 4 waves; wave covers 64 i (4 x 16), block 256 i.
// j streamed in 16-wide tiles (32 tiles per split). All frags from global
// K-major layout: lane(m,quad) reads [(n*20 + kc*4+quad)*4096 + row]*8 —
// 16 consecutive rows per quad = 256 B contiguous (coalesced dwordx4).
// mfma_f32_16x16x32_f16: C col = lane&15 (=m -> j), row = quad*4+reg.
// A-frags pinned resident via empty asm (defeats rematerialization).
// ---------------------------------------------------------------------------
__global__ __launch_bounds__(256, 2)
void mfma_nn_kernel(const f16* __restrict__ Qh, const f16* __restrict__ Ql,
                    const f16* __restrict__ Ph, const f16* __restrict__ Pl,
                    const float* __restrict__ pn_g,
                    unsigned long long* __restrict__ partial) {
    const int iblk = blockIdx.x, n = blockIdx.y, split = blockIdx.z;
    const int tid  = threadIdx.x;
    const int wave = tid >> 6, lane = tid & 63;
    const int m = lane & 15, quad = lane >> 4;

    const int irow0 = iblk * 256 + wave * 64;

    // ---- A fragments, loaded once and PINNED resident (160 VGPR) ----
    f16x8 Ah[4][5], Al[4][5];
    #pragma unroll
    for (int is = 0; is < 4; ++is)
        #pragma unroll
        for (int kc = 0; kc < 5; ++kc) {
            const size_t off = ((size_t)(n * 20 + kc * 4 + quad) * HW_ +
                                irow0 + is * 16 + m) * 8;
            Ah[is][kc] = *(const f16x8*)(Qh + off);
            Al[is][kc] = *(const f16x8*)(Ql + off);
        }
    // opaque to the optimizer: values can no longer be rematerialized
    #pragma unroll
    for (int is = 0; is < 4; ++is)
        #pragma unroll
        for (int kc = 0; kc < 5; ++kc)
            asm volatile("" : "+v"(Ah[is][kc]), "+v"(Al[is][kc]));

    float    bd[4][4];
    unsigned bj[4][4];
    #pragma unroll
    for (int is = 0; is < 4; ++is)
        #pragma unroll
        for (int rg = 0; rg < 4; ++rg) { bd[is][rg] = 3.0e38f; bj[is][rg] = 0u; }

    for (int jt = 0; jt < 32; ++jt) {
        const int j0 = split * 512 + jt * 16;
        const float pnv = pn_g[n * HW_ + j0 + m];   // this lane's j column

        f32x4 Cf[4];
        #pragma unroll
        for (int is = 0; is < 4; ++is) Cf[is] = (f32x4){0.f, 0.f, 0.f, 0.f};

        #pragma unroll
        for (int kc = 0; kc < 5; ++kc) {
            const size_t boff = ((size_t)(n * 20 + kc * 4 + quad) * HW_ +
                                 j0 + m) * 8;
            const f16x8 bh = *(const f16x8*)(Ph + boff);
            const f16x8 bl = *(const f16x8*)(Pl + boff);
            #pragma unroll
            for (int is = 0; is < 4; ++is) {
                Cf[is] = __builtin_amdgcn_mfma_f32_16x16x32_f16(
                    Ah[is][kc], bh, Cf[is], 0, 0, 0);
                Cf[is] = __builtin_amdgcn_mfma_f32_16x16x32_f16(
                    Al[is][kc], bh, Cf[is], 0, 0, 0);
                Cf[is] = __builtin_amdgcn_mfma_f32_16x16x32_f16(
                    Ah[is][kc], bl, Cf[is], 0, 0, 0);
            }
        }

        // epilogue: d' = pn - 2*cross (qn added in finalize); strict <
        // keeps earliest j within a lane (j increases with jt).
        #pragma unroll
        for (int is = 0; is < 4; ++is)
            #pragma unroll
            for (int rg = 0; rg < 4; ++rg) {
                const float d = fmaf(Cf[is][rg], -2.f, pnv);
                if (d < bd[is][rg]) {
                    bd[is][rg] = d;
                    bj[is][rg] = (unsigned)(j0 + m);
                }
            }
    }

    // ---- reduce across the 16 m-lanes (same quad = same i rows) ----
    #pragma unroll
    for (int is = 0; is < 4; ++is)
        #pragma unroll
        for (int rg = 0; rg < 4; ++rg) {
            float    d = bd[is][rg];
            unsigned j = bj[is][rg];
            #pragma unroll
            for (int off = 1; off < 16; off <<= 1) {
                const float    od = __shfl_xor(d, off, 64);
                const unsigned oj = __shfl_xor(j, off, 64);
                const bool take = (od < d) || (od == d && oj < j);
                d = take ? od : d;
                j = take ? oj : j;
            }
            if (m == 0) {
                const int i = irow0 + is * 16 + quad * 4 + rg;
                partial[(size_t)(split * N_ + n) * HW_ + i] =
                    ((unsigned long long)j << 32) |
                    (unsigned long long)__float_as_uint(d);
            }
        }
}

// ---------------------------------------------------------------------------
// Kernel 3: reduce splits, add qn, decode, write outputs (float32)
// ---------------------------------------------------------------------------
__global__ __launch_bounds__(256)
void finalize_mfma_kernel(const unsigned long long* __restrict__ partial,
                          const float* __restrict__ qn_g,
                          float* __restrict__ out) {
    const int id  = blockIdx.x * 256 + threadIdx.x;   // 0..16383
    const int n   = id >> 12;
    const int pix = id & 4095;
    float    bd = 3.0e38f;
    unsigned bj = 0u;
    #pragma unroll
    for (int sp = 0; sp < SPLITS_M; ++sp) {
        const unsigned long long v = partial[(size_t)(sp * N_ + n) * HW_ + pix];
        const float    d = __uint_as_float((unsigned)(v & 0xffffffffull));
        const unsigned j = (unsigned)(v >> 32);
        const bool take = (d < bd) || (d == bd && j < bj);
        bd = take ? d : bd;
        bj = take ? j : bj;
    }
    out[n * 2 * HW_ + pix]            = (float)(bj >> 6);          // idy
    out[n * 2 * HW_ + HW_ + pix]      = (float)(bj & 63);          // idx_x
    out[N_ * 2 * HW_ + n * HW_ + pix] = bd + qn_g[n * HW_ + pix];  // nnd
}

// ===========================================================================
// Fallback path (fp32 vector, R4 structure) + helpers
// ===========================================================================
__global__ __launch_bounds__(256)
void prep_norms_kernel(const float* __restrict__ s,
                       const float* __restrict__ t,
                       float* __restrict__ pn,
                       float* __restrict__ qn) {
    const int gid   = blockIdx.x * 256 + threadIdx.x;
    const int which = gid >> 14;
    const int id    = gid & 16383;
    const int n     = id >> 12;
    const int pix   = id & 4095;
    const int y = pix >> 6, x = pix & 63;
    const float* base = (which ? s : t) + n * (C_ * HW_);
    float acc = 0.f;
    for (int c = 0; c < C_; ++c) {
        const float* bc = base + c * HW_;
        #pragma unroll
        for (int dy = 0; dy < 3; ++dy) {
            const float* br = bc + iclamp(y + dy - 1, 0, H_ - 1) * W_;
            #pragma unroll
            for (int dx = 0; dx < 3; ++dx) {
                float v = br[iclamp(x + dx - 1, 0, W_ - 1)];
                acc += v * v;
            }
        }
    }
    (which ? qn : pn)[id] = acc;
}

__global__ __launch_bounds__(256)
void patchmatch_main_kernel(const float* __restrict__ s,
                            const float* __restrict__ t,
                            const float* __restrict__ pn_g,
                            const float* __restrict__ qn_g,
                            unsigned long long* __restrict__ partial) {
    const int yq    = blockIdx.x;
    const int n     = blockIdx.y;
    const int split = blockIdx.z;
    const int tid  = threadIdx.x;
    const int tx   = tid & 15;
    const int ty   = tid >> 4;
    const int i0   = ty * 4;
    const int jrow = tx >> 2;
    const int jx0  = (tx & 3) * 16;

    __shared__ float qS[C_][3][68];
    __shared__ float tS[C_][6][68];
    __shared__ float qnS[W_];

    const float* sb = s + n * (C_ * HW_);
    const float* tb = t + n * (C_ * HW_);

    #pragma unroll
    for (int k = 0; k < 3; ++k) {
        const int id = tid + k * 256;
        const int sg = id & 15;
        const int c  = (id >> 4) & 15;
        const int r  = id >> 8;
        const int gr = iclamp(yq + r - 1, 0, H_ - 1);
        const float4 v = *(const float4*)&sb[c * HW_ + gr * W_ + sg * 4];
        float* dst = &qS[c][r][1 + sg * 4];
        dst[0] = v.x; dst[1] = v.y; dst[2] = v.z; dst[3] = v.w;
    }
    if (tid < 48) {
        const int c  = tid & 15;
        const int r  = tid >> 4;
        const int gr = iclamp(yq + r - 1, 0, H_ - 1);
        qS[c][r][0]  = sb[c * HW_ + gr * W_];
        qS[c][r][65] = sb[c * HW_ + gr * W_ + 63];
    }
    if (tid < W_) qnS[tid] = qn_g[n * HW_ + yq * W_ + tid];

    unsigned long long best[4] = {~0ull, ~0ull, ~0ull, ~0ull};

    for (int ytl = 0; ytl < TILES_PER_SPLIT_V; ++ytl) {
        const int yt = split * TILES_PER_SPLIT_V + ytl;
        __syncthreads();
        #pragma unroll
        for (int k = 0; k < 6; ++k) {
            const int id = tid + k * 256;
            const int sg = id & 15;
            const int c  = (id >> 4) & 15;
            const int r  = id >> 8;
            const int gr = iclamp(4 * yt + r - 1, 0, H_ - 1);
            const float4 v = *(const float4*)&tb[c * HW_ + gr * W_ + sg * 4];
            float* dst = &tS[c][r][1 + sg * 4];
            dst[0] = v.x; dst[1] = v.y; dst[2] = v.z; dst[3] = v.w;
        }
        if (tid < 96) {
            const int c  = tid & 15;
            const int r  = tid >> 4;
            const int gr = iclamp(4 * yt + r - 1, 0, H_ - 1);
            tS[c][r][0]  = tb[c * HW_ + gr * W_];
            tS[c][r][65] = tb[c * HW_ + gr * W_ + 63];
        }
        __syncthreads();

        float acc[4][16];
        #pragma unroll
        for (int a = 0; a < 4; ++a)
            #pragma unroll
            for (int b = 0; b < 16; ++b) acc[a][b] = 0.f;

        for (int c = 0; c < C_; ++c) {
            #pragma unroll
            for (int dy = 0; dy < 3; ++dy) {
                float qv[6], tv[18];
                *(float4*)&qv[0] = *(const float4*)&qS[c][dy][i0];
                *(float2*)&qv[4] = *(const float2*)&qS[c][dy][i0 + 4];
                const float* trow = &tS[c][jrow + dy][jx0];
                *(float4*)&tv[0]  = *(const float4*)&trow[0];
                *(float4*)&tv[4]  = *(const float4*)&trow[4];
                *(float4*)&tv[8]  = *(const float4*)&trow[8];
                *(float4*)&tv[12] = *(const float4*)&trow[12];
                *(float2*)&tv[16] = *(const float2*)&trow[16];
                #pragma unroll
                for (int dx = 0; dx < 3; ++dx)
                    #pragma unroll
                    for (int a = 0; a < 4; ++a)
                        #pragma unroll
                        for (int b = 0; b < 16; ++b)
                            acc[a][b] += qv[a + dx] * tv[b + dx];
            }
        }

        const int jbase = yt * 256 + jrow * W_ + jx0;
        float pnv[16];
        const float* png = &pn_g[n * HW_ + jbase];
        *(float4*)&pnv[0]  = *(const float4*)&png[0];
        *(float4*)&pnv[4]  = *(const float4*)&png[4];
        *(float4*)&pnv[8]  = *(const float4*)&png[8];
        *(float4*)&pnv[12] = *(const float4*)&png[12];
        #pragma unroll
        for (int a = 0; a < 4; ++a) {
            const float qn = qnS[i0 + a];
            #pragma unroll
            for (int b = 0; b < 16; ++b) {
                const float d2 = qn + pnv[b] - 2.f * acc[a][b];
                unsigned long long cand =
                    ((unsigned long long)__float_as_uint(d2) << 32) |
                    (unsigned)(jbase + b);
                best[a] = cand < best[a] ? cand : best[a];
            }
        }
    }

    #pragma unroll
    for (int a = 0; a < 4; ++a) {
        unsigned long long v = best[a];
        #pragma unroll
        for (int mm = 8; mm >= 1; mm >>= 1) {
            unsigned long long o = __shfl_xor(v, mm, 64);
            v = o < v ? o : v;
        }
        best[a] = v;
    }
    if (tx == 0) {
        #pragma unroll
        for (int a = 0; a < 4; ++a)
            partial[((split * N_ + n) * HW_) + yq * W_ + i0 + a] = best[a];
    }
}

__global__ __launch_bounds__(256)
void finalize_kernel(const unsigned long long* __restrict__ partial,
                     float* __restrict__ out) {
    const int id  = blockIdx.x * 256 + threadIdx.x;
    const int n   = id >> 12;
    const int pix = id & 4095;
    unsigned long long best = ~0ull;
    #pragma unroll
    for (int sp = 0; sp < SPLITS_V; ++sp) {
        unsigned long long v = partial[(sp * N_ + n) * HW_ + pix];
        best = v < best ? v : best;
    }
    const unsigned j = (unsigned)(best & 0xffffffffu);
    const float d2 = __uint_as_float((unsigned)(best >> 32));
    out[n * 2 * HW_ + pix]            = (float)(j >> 6);
    out[n * 2 * HW_ + HW_ + pix]      = (float)(j & 63);
    out[N_ * 2 * HW_ + n * HW_ + pix] = d2;
}

__global__ __launch_bounds__(256)
void patchmatch_mono_kernel(const float* __restrict__ s,
                            const float* __restrict__ t,
                            float* __restrict__ out) {
    const int yq  = blockIdx.x;
    const int n   = blockIdx.y;
    const int tid = threadIdx.x;
    const int tx  = tid & 15;
    const int ty  = tid >> 4;
    const int i0  = ty * 4;
    const int jrow = tx >> 3;
    const int jx0  = (tx & 7) * 8;

    __shared__ float qS[C_][3][68];
    __shared__ float tS[C_][4][68];
    __shared__ float pnS[HW_];
    __shared__ float qnS[W_];

    const float* sb = s + n * (C_ * HW_);
    const float* tb = t + n * (C_ * HW_);

    for (int jj = tid; jj < HW_; jj += 256) {
        const int y = jj >> 6, x = jj & 63;
        float acc = 0.f;
        for (int c = 0; c < C_; ++c) {
            const float* tc = tb + c * HW_;
            #pragma unroll
            for (int dy = 0; dy < 3; ++dy) {
                const float* tr = tc + iclamp(y + dy - 1, 0, H_ - 1) * W_;
                #pragma unroll
                for (int dx = 0; dx < 3; ++dx) {
                    float v = tr[iclamp(x + dx - 1, 0, W_ - 1)];
                    acc += v * v;
                }
            }
        }
        pnS[jj] = acc;
    }
    for (int idx = tid; idx < C_ * 3 * 66; idx += 256) {
        const int c   = idx / (3 * 66);
        const int rem = idx - c * (3 * 66);
        const int rr  = rem / 66;
        const int xi  = rem - rr * 66;
        qS[c][rr][xi] = sb[c * HW_ + iclamp(yq + rr - 1, 0, H_ - 1) * W_ +
                           iclamp(xi - 1, 0, W_ - 1)];
    }
    __syncthreads();
    if (tid < W_) {
        float acc = 0.f;
        for (int c = 0; c < C_; ++c)
            #pragma unroll
            for (int dy = 0; dy < 3; ++dy)
                #pragma unroll
                for (int dx = 0; dx < 3; ++dx) {
                    float v = qS[c][dy][tid + dx];
                    acc += v * v;
                }
        qnS[tid] = acc;
    }

    unsigned long long best[4] = {~0ull, ~0ull, ~0ull, ~0ull};
    for (int yt = 0; yt < 32; ++yt) {
        __syncthreads();
        for (int idx = tid; idx < C_ * 4 * 66; idx += 256) {
            const int c   = idx / (4 * 66);
            const int rem = idx - c * (4 * 66);
            const int rr  = rem / 66;
            const int xi  = rem - rr * 66;
            tS[c][rr][xi] = tb[c * HW_ + iclamp(2 * yt + rr - 1, 0, H_ - 1) * W_ +
                               iclamp(xi - 1, 0, W_ - 1)];
        }
        __syncthreads();

        float acc[4][8];
        #pragma unroll
        for (int a = 0; a < 4; ++a)
            #pragma unroll
            for (int b = 0; b < 8; ++b) acc[a][b] = 0.f;

        for (int c = 0; c < C_; ++c) {
            #pragma unroll
            for (int dy = 0; dy < 3; ++dy) {
                float qv[8], tv[12];
                *(float4*)&qv[0] = *(const float4*)&qS[c][dy][i0];
                *(float4*)&qv[4] = *(const float4*)&qS[c][dy][i0 + 4];
                const float* trow = &tS[c][jrow + dy][jx0];
                *(float4*)&tv[0] = *(const float4*)&trow[0];
                *(float4*)&tv[4] = *(const float4*)&trow[4];
                *(float4*)&tv[8] = *(const float4*)&trow[8];
                #pragma unroll
                for (int dx = 0; dx < 3; ++dx)
                    #pragma unroll
                    for (int a = 0; a < 4; ++a)
                        #pragma unroll
                        for (int b = 0; b < 8; ++b)
                            acc[a][b] += qv[a + dx] * tv[b + dx];
            }
        }
        const int rbase = (2 * yt + jrow) * W_ + jx0;
        #pragma unroll
        for (int a = 0; a < 4; ++a) {
            const float qn = qnS[i0 + a];
            #pragma unroll
            for (int b = 0; b < 8; ++b) {
                const int j = rbase + b;
                const float d2 = qn + pnS[j] - 2.f * acc[a][b];
                unsigned long long cand =
                    ((unsigned long long)__float_as_uint(d2) << 32) | (unsigned)j;
                best[a] = cand < best[a] ? cand : best[a];
            }
        }
    }
    #pragma unroll
    for (int a = 0; a < 4; ++a) {
        unsigned long long v = best[a];
        #pragma unroll
        for (int mm = 8; mm >= 1; mm >>= 1) {
            unsigned long long o = __shfl_xor(v, mm, 64);
            v = o < v ? o : v;
        }
        best[a] = v;
    }
    if (tx == 0) {
        #pragma unroll
        for (int a = 0; a < 4; ++a) {
            const int x = i0 + a;
            const unsigned j = (unsigned)(best[a] & 0xffffffffu);
            const float d2 = __uint_as_float((unsigned)(best[a] >> 32));
            const int pix = yq * W_ + x;
            out[n * 2 * HW_ + pix]            = (float)(j >> 6);
            out[n * 2 * HW_ + HW_ + pix]      = (float)(j & 63);
            out[N_ * 2 * HW_ + n * HW_ + pix] = d2;
        }
    }
}

// ===========================================================================
extern "C" void kernel_launch(void* const* d_in, const int* in_sizes, int n_in,
                              void* d_out, int out_size, void* d_ws, size_t ws_size,
                              hipStream_t stream) {
    const float* s = (const float*)d_in[0];
    const float* t = (const float*)d_in[1];
    float* out = (float*)d_out;

    // MFMA ws layout:
    //   pn [4][4096] f32 | qn [4][4096] f32 | partial [8][4][4096] u64 |
    //   Qh | Ql | Ph | Pl   each K-major [4][20][4096][8] f16 (5.24 MB)
    const size_t norm_b  = (size_t)N_ * HW_ * 4;
    const size_t part_b  = (size_t)SPLITS_M * N_ * HW_ * 8;
    const size_t desc_b  = (size_t)N_ * HW_ * K_ * 2;
    const size_t need_m  = 2 * norm_b + part_b + 4 * desc_b;     // ~22 MB

    if (ws_size >= need_m) {
        char* w = (char*)d_ws;
        float* pn = (float*)w;                       w += norm_b;
        float* qn = (float*)w;                       w += norm_b;
        unsigned long long* partial = (unsigned long long*)w; w += part_b;
        f16* Qh = (f16*)w;  w += desc_b;
        f16* Ql = (f16*)w;  w += desc_b;
        f16* Ph = (f16*)w;  w += desc_b;
        f16* Pl = (f16*)w;

        build_desc_norms_kernel<<<dim3(64, N_, 2), 256, 0, stream>>>(
            s, t, Qh, Ql, Ph, Pl, pn, qn);
        mfma_nn_kernel<<<dim3(16, N_, SPLITS_M), 256, 0, stream>>>(
            Qh, Ql, Ph, Pl, pn, partial);
        finalize_mfma_kernel<<<64, 256, 0, stream>>>(partial, qn, out);
        return;
    }

    // Fallback: fp32 vector path
    const size_t need_v = 2 * norm_b + (size_t)SPLITS_V * N_ * HW_ * 8;
    if (ws_size >= need_v) {
        float* pn = (float*)d_ws;
        float* qn = pn + N_ * HW_;
        unsigned long long* partial =
            (unsigned long long*)((char*)d_ws + 2 * norm_b);
        prep_norms_kernel<<<128, 256, 0, stream>>>(s, t, pn, qn);
        dim3 grid(H_, N_, SPLITS_V);
        patchmatch_main_kernel<<<grid, 256, 0, stream>>>(s, t, pn, qn, partial);
        finalize_kernel<<<64, 256, 0, stream>>>(partial, out);
        return;
    }

    dim3 grid(H_, N_);
    patchmatch_mono_kernel<<<grid, 256, 0, stream>>>(s, t, out);
}

// Round 10
// 177.590 us; speedup vs baseline: 1.0418x; 1.0388x over previous
//
#include <hip/hip_runtime.h>

// PatchMatch brute-force NN on MI355X.
// s,t (4,16,64,64) fp32; descriptor = 3x3 replicate-padded patch, K=144 (pad 160).
// d2(i,j) = qn_i - 2*cross(i,j) + pn_j; argmin_j (ties -> smallest j).
// Outputs (flat, ALL FLOAT32): nnf (4,2,64,64) then nnd (4,1,64,64).
//
// R10 vs R9 (121us, tile time ~9.1k cyc = 10 B-loads x ~900cyc SERIALIZED;
// A-frags were already resident (AGPRs) — remat theory was wrong, register
// pressure left no room to keep B-loads in flight):
//  - wave i-footprint 64->32 (A = 80 VGPR) frees registers for explicit
//    DOUBLE-BUFFERED B fragments: jt loop unrolled x2 ping-pong, next tile's
//    10 loads issued before current tile's MFMAs -> latency overlapped.
//  - grid (32,4,8): 32 consecutive blocks share one B-slice (L2 locality).

#define N_  4
#define C_  16
#define H_  64
#define W_  64
#define HW_ 4096
#define K_  160              // 144 real + 16 zero-pad; 20 chunks of 8
#define SPLITS_M 8           // j-splits; 512 j per split, 32 tiles of 16

#define SPLITS_V 4           // fallback j-splits
#define TILES_PER_SPLIT_V 4

typedef _Float16 f16;
typedef _Float16 f16x8 __attribute__((ext_vector_type(8)));
typedef float    f32x4 __attribute__((ext_vector_type(4)));

__device__ __forceinline__ int iclamp(int v, int lo, int hi) {
    return v < lo ? lo : (v > hi ? hi : v);
}

// ---------------------------------------------------------------------------
// Kernel 1: build K-major fp16 hi/lo descriptors AND squared norms.
// Layout: D[(n*20 + kk)*4096 + pix][8], kk = k/8, k = d*16 + c (d = dy*3+dx).
// kk 18,19 zero. grid (64, N_, 2): z=0 -> t->Ph/Pl+pn, z=1 -> s->Qh/Ql+qn.
// ---------------------------------------------------------------------------
__global__ __launch_bounds__(256)
void build_desc_norms_kernel(const float* __restrict__ s,
                             const float* __restrict__ t,
                             f16* __restrict__ Qh, f16* __restrict__ Ql,
                             f16* __restrict__ Ph, f16* __restrict__ Pl,
                             float* __restrict__ pn,
                             float* __restrict__ qn) {
    const int pix = blockIdx.x * 64 + (threadIdx.x >> 2);
    const int n   = blockIdx.y;
    const int src = blockIdx.z;                 // 0: t, 1: s
    const int y = pix >> 6, x = pix & 63;
    const float* img = (src ? s : t) + n * (C_ * HW_);
    f16* Dh = (src ? Qh : Ph);
    f16* Dl = (src ? Ql : Pl);
    float nacc = 0.f;
    #pragma unroll
    for (int q = 0; q < 5; ++q) {
        const int kk = (threadIdx.x & 3) * 5 + q;    // 0..19
        f16x8 hv, lv;
        if (kk < 18) {
            const int d  = kk >> 1;                  // 0..8
            const int c0 = (kk & 1) * 8;
            const int dy = (d >= 6) ? 2 : (d >= 3 ? 1 : 0);
            const int dx = d - dy * 3;
            const int ys = iclamp(y + dy - 1, 0, H_ - 1);
            const int xs = iclamp(x + dx - 1, 0, W_ - 1);
            const float* p0 = img + c0 * HW_ + ys * W_ + xs;
            #pragma unroll
            for (int cc = 0; cc < 8; ++cc) {
                const float v = p0[cc * HW_];
                const f16 h = (f16)v;
                hv[cc] = h;
                lv[cc] = (f16)(v - (float)h);
                nacc += v * v;
            }
        } else {
            #pragma unroll
            for (int cc = 0; cc < 8; ++cc) { hv[cc] = (f16)0.f; lv[cc] = (f16)0.f; }
        }
        const size_t off = ((size_t)(n * 20 + kk) * HW_ + pix) * 8;
        *(f16x8*)&Dh[off] = hv;
        *(f16x8*)&Dl[off] = lv;
    }
    nacc += __shfl_xor(nacc, 1, 64);
    nacc += __shfl_xor(nacc, 2, 64);
    if ((threadIdx.x & 3) == 0)
        (src ? qn : pn)[n * HW_ + pix] = nacc;
}

// ---------------------------------------------------------------------------
// Kernel 2: MFMA GEMM + fused argmin, no LDS / no barriers, register
// double-buffered B. Block 256 thr = 4 waves; wave covers 32 i (2 x 16),
// block 128 i. j streamed in 16-wide tiles, 32 per split, unrolled x2.
// ---------------------------------------------------------------------------
__global__ __launch_bounds__(256, 2)
void mfma_nn_kernel(const f16* __restrict__ Qh, const f16* __restrict__ Ql,
                    const f16* __restrict__ Ph, const f16* __restrict__ Pl,
                    const float* __restrict__ pn_g,
                    unsigned long long* __restrict__ partial) {
    const int iblk = blockIdx.x, n = blockIdx.y, split = blockIdx.z;
    const int tid  = threadIdx.x;
    const int wave = tid >> 6, lane = tid & 63;
    const int m = lane & 15, quad = lane >> 4;

    const int irow0 = iblk * 128 + wave * 32;

    // ---- A fragments, loaded once, resident (80 VGPR) ----
    f16x8 Ah[2][5], Al[2][5];
    #pragma unroll
    for (int is = 0; is < 2; ++is)
        #pragma unroll
        for (int kc = 0; kc < 5; ++kc) {
            const size_t off = ((size_t)(n * 20 + kc * 4 + quad) * HW_ +
                                irow0 + is * 16 + m) * 8;
            Ah[is][kc] = *(const f16x8*)(Qh + off);
            Al[is][kc] = *(const f16x8*)(Ql + off);
        }

    float    bd[2][4];
    unsigned bj[2][4];
    #pragma unroll
    for (int is = 0; is < 2; ++is)
        #pragma unroll
        for (int rg = 0; rg < 4; ++rg) { bd[is][rg] = 3.0e38f; bj[is][rg] = 0u; }

    const int jbase0 = split * 512;
    const f16*   Phb = Ph + (size_t)m * 8;
    const f16*   Plb = Pl + (size_t)m * 8;
    const float* png = pn_g + n * HW_ + m;

    // double-buffered B fragments (2 x 40 VGPR) + pn
    f16x8 b0h[5], b0l[5], b1h[5], b1l[5];
    float pn0, pn1;

    #define LOAD_B(BH, BL, PN, J0)                                         \
        {   const int _j0 = (J0);                                          \
            _Pragma("unroll")                                              \
            for (int kc = 0; kc < 5; ++kc) {                               \
                const size_t boff =                                        \
                    ((size_t)(n * 20 + kc * 4 + quad) * HW_ + _j0) * 8;    \
                BH[kc] = *(const f16x8*)(Phb + boff);                      \
                BL[kc] = *(const f16x8*)(Plb + boff);                      \
            }                                                              \
            PN = png[_j0];                                                 \
        }

    #define DO_TILE(BH, BL, PN, JT)                                       \
        {   f32x4 Cf[2];                                                  \
            Cf[0] = (f32x4){0.f, 0.f, 0.f, 0.f};                          \
            Cf[1] = (f32x4){0.f, 0.f, 0.f, 0.f};                          \
            _Pragma("unroll")                                             \
            for (int kc = 0; kc < 5; ++kc)                                \
                _Pragma("unroll")                                         \
                for (int is = 0; is < 2; ++is) {                          \
                    Cf[is] = __builtin_amdgcn_mfma_f32_16x16x32_f16(      \
                        Ah[is][kc], BH[kc], Cf[is], 0, 0, 0);             \
                    Cf[is] = __builtin_amdgcn_mfma_f32_16x16x32_f16(      \
                        Al[is][kc], BH[kc], Cf[is], 0, 0, 0);             \
                    Cf[is] = __builtin_amdgcn_mfma_f32_16x16x32_f16(      \
                        Ah[is][kc], BL[kc], Cf[is], 0, 0, 0);             \
                }                                                         \
            _Pragma("unroll")                                             \
            for (int is = 0; is < 2; ++is)                                \
                _Pragma("unroll")                                         \
                for (int rg = 0; rg < 4; ++rg) {                          \
                    const float d = fmaf(Cf[is][rg], -2.f, PN);           \
                    if (d < bd[is][rg]) {                                 \
                        bd[is][rg] = d;                                   \
                        bj[is][rg] = (unsigned)((JT) * 16 + m);           \
                    }                                                     \
                }                                                         \
        }

    LOAD_B(b0h, b0l, pn0, jbase0)                      // tile 0
    for (int jt = 0; jt < 32; jt += 2) {
        LOAD_B(b1h, b1l, pn1, jbase0 + (jt + 1) * 16)  // prefetch odd tile
        DO_TILE(b0h, b0l, pn0, jt)
        {
            const int nx = (jt + 2 < 32) ? (jt + 2) : 0;   // safe dummy at end
            LOAD_B(b0h, b0l, pn0, jbase0 + nx * 16)        // prefetch even tile
        }
        DO_TILE(b1h, b1l, pn1, jt + 1)
    }
    #undef LOAD_B
    #undef DO_TILE

    // ---- reduce across the 16 m-lanes (same quad = same i rows) ----
    #pragma unroll
    for (int is = 0; is < 2; ++is)
        #pragma unroll
        for (int rg = 0; rg < 4; ++rg) {
            float    d = bd[is][rg];
            unsigned j = (unsigned)jbase0 + bj[is][rg];    // global j
            #pragma unroll
            for (int off = 1; off < 16; off <<= 1) {
                const float    od = __shfl_xor(d, off, 64);
                const unsigned oj = __shfl_xor(j, off, 64);
                const bool take = (od < d) || (od == d && oj < j);
                d = take ? od : d;
                j = take ? oj : j;
            }
            if (m == 0) {
                const int i = irow0 + is * 16 + quad * 4 + rg;
                partial[(size_t)(split * N_ + n) * HW_ + i] =
                    ((unsigned long long)j << 32) |
                    (unsigned long long)__float_as_uint(d);
            }
        }
}

// ---------------------------------------------------------------------------
// Kernel 3: reduce splits, add qn, decode, write outputs (float32)
// ---------------------------------------------------------------------------
__global__ __launch_bounds__(256)
void finalize_mfma_kernel(const unsigned long long* __restrict__ partial,
                          const float* __restrict__ qn_g,
                          float* __restrict__ out) {
    const int id  = blockIdx.x * 256 + threadIdx.x;   // 0..16383
    const int n   = id >> 12;
    const int pix = id & 4095;
    float    bd = 3.0e38f;
    unsigned bj = 0u;
    #pragma unroll
    for (int sp = 0; sp < SPLITS_M; ++sp) {
        const unsigned long long v = partial[(size_t)(sp * N_ + n) * HW_ + pix];
        const float    d = __uint_as_float((unsigned)(v & 0xffffffffull));
        const unsigned j = (unsigned)(v >> 32);
        const bool take = (d < bd) || (d == bd && j < bj);
        bd = take ? d : bd;
        bj = take ? j : bj;
    }
    out[n * 2 * HW_ + pix]            = (float)(bj >> 6);          // idy
    out[n * 2 * HW_ + HW_ + pix]      = (float)(bj & 63);          // idx_x
    out[N_ * 2 * HW_ + n * HW_ + pix] = bd + qn_g[n * HW_ + pix];  // nnd
}

// ===========================================================================
// Fallback path (fp32 vector, R4 structure) + helpers
// ===========================================================================
__global__ __launch_bounds__(256)
void prep_norms_kernel(const float* __restrict__ s,
                       const float* __restrict__ t,
                       float* __restrict__ pn,
                       float* __restrict__ qn) {
    const int gid   = blockIdx.x * 256 + threadIdx.x;
    const int which = gid >> 14;
    const int id    = gid & 16383;
    const int n     = id >> 12;
    const int pix   = id & 4095;
    const int y = pix >> 6, x = pix & 63;
    const float* base = (which ? s : t) + n * (C_ * HW_);
    float acc = 0.f;
    for (int c = 0; c < C_; ++c) {
        const float* bc = base + c * HW_;
        #pragma unroll
        for (int dy = 0; dy < 3; ++dy) {
            const float* br = bc + iclamp(y + dy - 1, 0, H_ - 1) * W_;
            #pragma unroll
            for (int dx = 0; dx < 3; ++dx) {
                float v = br[iclamp(x + dx - 1, 0, W_ - 1)];
                acc += v * v;
            }
        }
    }
    (which ? qn : pn)[id] = acc;
}

__global__ __launch_bounds__(256)
void patchmatch_main_kernel(const float* __restrict__ s,
                            const float* __restrict__ t,
                            const float* __restrict__ pn_g,
                            const float* __restrict__ qn_g,
                            unsigned long long* __restrict__ partial) {
    const int yq    = blockIdx.x;
    const int n     = blockIdx.y;
    const int split = blockIdx.z;
    const int tid  = threadIdx.x;
    const int tx   = tid & 15;
    const int ty   = tid >> 4;
    const int i0   = ty * 4;
    const int jrow = tx >> 2;
    const int jx0  = (tx & 3) * 16;

    __shared__ float qS[C_][3][68];
    __shared__ float tS[C_][6][68];
    __shared__ float qnS[W_];

    const float* sb = s + n * (C_ * HW_);
    const float* tb = t + n * (C_ * HW_);

    #pragma unroll
    for (int k = 0; k < 3; ++k) {
        const int id = tid + k * 256;
        const int sg = id & 15;
        const int c  = (id >> 4) & 15;
        const int r  = id >> 8;
        const int gr = iclamp(yq + r - 1, 0, H_ - 1);
        const float4 v = *(const float4*)&sb[c * HW_ + gr * W_ + sg * 4];
        float* dst = &qS[c][r][1 + sg * 4];
        dst[0] = v.x; dst[1] = v.y; dst[2] = v.z; dst[3] = v.w;
    }
    if (tid < 48) {
        const int c  = tid & 15;
        const int r  = tid >> 4;
        const int gr = iclamp(yq + r - 1, 0, H_ - 1);
        qS[c][r][0]  = sb[c * HW_ + gr * W_];
        qS[c][r][65] = sb[c * HW_ + gr * W_ + 63];
    }
    if (tid < W_) qnS[tid] = qn_g[n * HW_ + yq * W_ + tid];

    unsigned long long best[4] = {~0ull, ~0ull, ~0ull, ~0ull};

    for (int ytl = 0; ytl < TILES_PER_SPLIT_V; ++ytl) {
        const int yt = split * TILES_PER_SPLIT_V + ytl;
        __syncthreads();
        #pragma unroll
        for (int k = 0; k < 6; ++k) {
            const int id = tid + k * 256;
            const int sg = id & 15;
            const int c  = (id >> 4) & 15;
            const int r  = id >> 8;
            const int gr = iclamp(4 * yt + r - 1, 0, H_ - 1);
            const float4 v = *(const float4*)&tb[c * HW_ + gr * W_ + sg * 4];
            float* dst = &tS[c][r][1 + sg * 4];
            dst[0] = v.x; dst[1] = v.y; dst[2] = v.z; dst[3] = v.w;
        }
        if (tid < 96) {
            const int c  = tid & 15;
            const int r  = tid >> 4;
            const int gr = iclamp(4 * yt + r - 1, 0, H_ - 1);
            tS[c][r][0]  = tb[c * HW_ + gr * W_];
            tS[c][r][65] = tb[c * HW_ + gr * W_ + 63];
        }
        __syncthreads();

        float acc[4][16];
        #pragma unroll
        for (int a = 0; a < 4; ++a)
            #pragma unroll
            for (int b = 0; b < 16; ++b) acc[a][b] = 0.f;

        for (int c = 0; c < C_; ++c) {
            #pragma unroll
            for (int dy = 0; dy < 3; ++dy) {
                float qv[6], tv[18];
                *(float4*)&qv[0] = *(const float4*)&qS[c][dy][i0];
                *(float2*)&qv[4] = *(const float2*)&qS[c][dy][i0 + 4];
                const float* trow = &tS[c][jrow + dy][jx0];
                *(float4*)&tv[0]  = *(const float4*)&trow[0];
                *(float4*)&tv[4]  = *(const float4*)&trow[4];
                *(float4*)&tv[8]  = *(const float4*)&trow[8];
                *(float4*)&tv[12] = *(const float4*)&trow[12];
                *(float2*)&tv[16] = *(const float2*)&trow[16];
                #pragma unroll
                for (int dx = 0; dx < 3; ++dx)
                    #pragma unroll
                    for (int a = 0; a < 4; ++a)
                        #pragma unroll
                        for (int b = 0; b < 16; ++b)
                            acc[a][b] += qv[a + dx] * tv[b + dx];
            }
        }

        const int jbase = yt * 256 + jrow * W_ + jx0;
        float pnv[16];
        const float* png = &pn_g[n * HW_ + jbase];
        *(float4*)&pnv[0]  = *(const float4*)&png[0];
        *(float4*)&pnv[4]  = *(const float4*)&png[4];
        *(float4*)&pnv[8]  = *(const float4*)&png[8];
        *(float4*)&pnv[12] = *(const float4*)&png[12];
        #pragma unroll
        for (int a = 0; a < 4; ++a) {
            const float qn = qnS[i0 + a];
            #pragma unroll
            for (int b = 0; b < 16; ++b) {
                const float d2 = qn + pnv[b] - 2.f * acc[a][b];
                unsigned long long cand =
                    ((unsigned long long)__float_as_uint(d2) << 32) |
                    (unsigned)(jbase + b);
                best[a] = cand < best[a] ? cand : best[a];
            }
        }
    }

    #pragma unroll
    for (int a = 0; a < 4; ++a) {
        unsigned long long v = best[a];
        #pragma unroll
        for (int mm = 8; mm >= 1; mm >>= 1) {
            unsigned long long o = __shfl_xor(v, mm, 64);
            v = o < v ? o : v;
        }
        best[a] = v;
    }
    if (tx == 0) {
        #pragma unroll
        for (int a = 0; a < 4; ++a)
            partial[((split * N_ + n) * HW_) + yq * W_ + i0 + a] = best[a];
    }
}

__global__ __launch_bounds__(256)
void finalize_kernel(const unsigned long long* __restrict__ partial,
                     float* __restrict__ out) {
    const int id  = blockIdx.x * 256 + threadIdx.x;
    const int n   = id >> 12;
    const int pix = id & 4095;
    unsigned long long best = ~0ull;
    #pragma unroll
    for (int sp = 0; sp < SPLITS_V; ++sp) {
        unsigned long long v = partial[(sp * N_ + n) * HW_ + pix];
        best = v < best ? v : best;
    }
    const unsigned j = (unsigned)(best & 0xffffffffu);
    const float d2 = __uint_as_float((unsigned)(best >> 32));
    out[n * 2 * HW_ + pix]            = (float)(j >> 6);
    out[n * 2 * HW_ + HW_ + pix]      = (float)(j & 63);
    out[N_ * 2 * HW_ + n * HW_ + pix] = d2;
}

__global__ __launch_bounds__(256)
void patchmatch_mono_kernel(const float* __restrict__ s,
                            const float* __restrict__ t,
                            float* __restrict__ out) {
    const int yq  = blockIdx.x;
    const int n   = blockIdx.y;
    const int tid = threadIdx.x;
    const int tx  = tid & 15;
    const int ty  = tid >> 4;
    const int i0  = ty * 4;
    const int jrow = tx >> 3;
    const int jx0  = (tx & 7) * 8;

    __shared__ float qS[C_][3][68];
    __shared__ float tS[C_][4][68];
    __shared__ float pnS[HW_];
    __shared__ float qnS[W_];

    const float* sb = s + n * (C_ * HW_);
    const float* tb = t + n * (C_ * HW_);

    for (int jj = tid; jj < HW_; jj += 256) {
        const int y = jj >> 6, x = jj & 63;
        float acc = 0.f;
        for (int c = 0; c < C_; ++c) {
            const float* tc = tb + c * HW_;
            #pragma unroll
            for (int dy = 0; dy < 3; ++dy) {
                const float* tr = tc + iclamp(y + dy - 1, 0, H_ - 1) * W_;
                #pragma unroll
                for (int dx = 0; dx < 3; ++dx) {
                    float v = tr[iclamp(x + dx - 1, 0, W_ - 1)];
                    acc += v * v;
                }
            }
        }
        pnS[jj] = acc;
    }
    for (int idx = tid; idx < C_ * 3 * 66; idx += 256) {
        const int c   = idx / (3 * 66);
        const int rem = idx - c * (3 * 66);
        const int rr  = rem / 66;
        const int xi  = rem - rr * 66;
        qS[c][rr][xi] = sb[c * HW_ + iclamp(yq + rr - 1, 0, H_ - 1) * W_ +
                           iclamp(xi - 1, 0, W_ - 1)];
    }
    __syncthreads();
    if (tid < W_) {
        float acc = 0.f;
        for (int c = 0; c < C_; ++c)
            #pragma unroll
            for (int dy = 0; dy < 3; ++dy)
                #pragma unroll
                for (int dx = 0; dx < 3; ++dx) {
                    float v = qS[c][dy][tid + dx];
                    acc += v * v;
                }
        qnS[tid] = acc;
    }

    unsigned long long best[4] = {~0ull, ~0ull, ~0ull, ~0ull};
    for (int yt = 0; yt < 32; ++yt) {
        __syncthreads();
        for (int idx = tid; idx < C_ * 4 * 66; idx += 256) {
            const int c   = idx / (4 * 66);
            const int rem = idx - c * (4 * 66);
            const int rr  = rem / 66;
            const int xi  = rem - rr * 66;
            tS[c][rr][xi] = tb[c * HW_ + iclamp(2 * yt + rr - 1, 0, H_ - 1) * W_ +
                               iclamp(xi - 1, 0, W_ - 1)];
        }
        __syncthreads();

        float acc[4][8];
        #pragma unroll
        for (int a = 0; a < 4; ++a)
            #pragma unroll
            for (int b = 0; b < 8; ++b) acc[a][b] = 0.f;

        for (int c = 0; c < C_; ++c) {
            #pragma unroll
            for (int dy = 0; dy < 3; ++dy) {
                float qv[8], tv[12];
                *(float4*)&qv[0] = *(const float4*)&qS[c][dy][i0];
                *(float4*)&qv[4] = *(const float4*)&qS[c][dy][i0 + 4];
                const float* trow = &tS[c][jrow + dy][jx0];
                *(float4*)&tv[0] = *(const float4*)&trow[0];
                *(float4*)&tv[4] = *(const float4*)&trow[4];
                *(float4*)&tv[8] = *(const float4*)&trow[8];
                #pragma unroll
                for (int dx = 0; dx < 3; ++dx)
                    #pragma unroll
                    for (int a = 0; a < 4; ++a)
                        #pragma unroll
                        for (int b = 0; b < 8; ++b)
                            acc[a][b] += qv[a + dx] * tv[b + dx];
            }
        }
        const int rbase = (2 * yt + jrow) * W_ + jx0;
        #pragma unroll
        for (int a = 0; a < 4; ++a) {
            const float qn = qnS[i0 + a];
            #pragma unroll
            for (int b = 0; b < 8; ++b) {
                const int j = rbase + b;
                const float d2 = qn + pnS[j] - 2.f * acc[a][b];
                unsigned long long cand =
                    ((unsigned long long)__float_as_uint(d2) << 32) | (unsigned)j;
                best[a] = cand < best[a] ? cand : best[a];
            }
        }
    }
    #pragma unroll
    for (int a = 0; a < 4; ++a) {
        unsigned long long v = best[a];
        #pragma unroll
        for (int mm = 8; mm >= 1; mm >>= 1) {
            unsigned long long o = __shfl_xor(v, mm, 64);
            v = o < v ? o : v;
        }
        best[a] = v;
    }
    if (tx == 0) {
        #pragma unroll
        for (int a = 0; a < 4; ++a) {
            const int x = i0 + a;
            const unsigned j = (unsigned)(best[a] & 0xffffffffu);
            const float d2 = __uint_as_float((unsigned)(best[a] >> 32));
            const int pix = yq * W_ + x;
            out[n * 2 * HW_ + pix]            = (float)(j >> 6);
            out[n * 2 * HW_ + HW_ + pix]      = (float)(j & 63);
            out[N_ * 2 * HW_ + n * HW_ + pix] = d2;
        }
    }
}

// ===========================================================================
extern "C" void kernel_launch(void* const* d_in, const int* in_sizes, int n_in,
                              void* d_out, int out_size, void* d_ws, size_t ws_size,
                              hipStream_t stream) {
    const float* s = (const float*)d_in[0];
    const float* t = (const float*)d_in[1];
    float* out = (float*)d_out;

    // MFMA ws layout:
    //   pn [4][4096] f32 | qn [4][4096] f32 | partial [8][4][4096] u64 |
    //   Qh | Ql | Ph | Pl   each K-major [4][20][4096][8] f16 (5.24 MB)
    const size_t norm_b  = (size_t)N_ * HW_ * 4;
    const size_t part_b  = (size_t)SPLITS_M * N_ * HW_ * 8;
    const size_t desc_b  = (size_t)N_ * HW_ * K_ * 2;
    const size_t need_m  = 2 * norm_b + part_b + 4 * desc_b;     // ~22 MB

    if (ws_size >= need_m) {
        char* w = (char*)d_ws;
        float* pn = (float*)w;                       w += norm_b;
        float* qn = (float*)w;                       w += norm_b;
        unsigned long long* partial = (unsigned long long*)w; w += part_b;
        f16* Qh = (f16*)w;  w += desc_b;
        f16* Ql = (f16*)w;  w += desc_b;
        f16* Ph = (f16*)w;  w += desc_b;
        f16* Pl = (f16*)w;

        build_desc_norms_kernel<<<dim3(64, N_, 2), 256, 0, stream>>>(
            s, t, Qh, Ql, Ph, Pl, pn, qn);
        mfma_nn_kernel<<<dim3(32, N_, SPLITS_M), 256, 0, stream>>>(
            Qh, Ql, Ph, Pl, pn, partial);
        finalize_mfma_kernel<<<64, 256, 0, stream>>>(partial, qn, out);
        return;
    }

    // Fallback: fp32 vector path
    const size_t need_v = 2 * norm_b + (size_t)SPLITS_V * N_ * HW_ * 8;
    if (ws_size >= need_v) {
        float* pn = (float*)d_ws;
        float* qn = pn + N_ * HW_;
        unsigned long long* partial =
            (unsigned long long*)((char*)d_ws + 2 * norm_b);
        prep_norms_kernel<<<128, 256, 0, stream>>>(s, t, pn, qn);
        dim3 grid(H_, N_, SPLITS_V);
        patchmatch_main_kernel<<<grid, 256, 0, stream>>>(s, t, pn, qn, partial);
        finalize_kernel<<<64, 256, 0, stream>>>(partial, out);
        return;
    }

    dim3 grid(H_, N_);
    patchmatch_mono_kernel<<<grid, 256, 0, stream>>>(s, t, out);
}

// Round 11
// 132.422 us; speedup vs baseline: 1.3972x; 1.3411x over previous
//
#include <hip/hip_runtime.h>

// PatchMatch brute-force NN on MI355X.
// s,t (4,16,64,64) fp32; descriptor = 3x3 replicate-padded patch, K=144 (pad 160).
// d2(i,j) = qn_i - 2*cross(i,j) + pn_j; argmin_j (ties -> smallest j).
// Outputs (flat, ALL FLOAT32): nnf (4,2,64,64) then nnd (4,1,64,64).
//
// R11 vs R10 (114us, HBM-latency-bound: 52MB HBM fetch, waves privately
// re-loading shared B, no XCD locality):
//  - B staged into LDS via ASYNC global_load_lds (width 16), double-buffered,
//    shared by all 4 waves (-4x B load traffic). One barrier per 32-j tile.
//  - 1D grid 512 blocks, split = bid&3 -> each (n,split) B-slice (1.3MB) pins
//    to one XCD's L2 under round-robin dispatch. All blocks resident (2/CU).
//  - build_desc rewritten: LDS row staging -> fully coalesced 16B stores.

#define N_  4
#define C_  16
#define H_  64
#define W_  64
#define HW_ 4096
#define K_  160              // 144 real + 16 zero-pad; 20 chunks of 8
#define SPLITS_M 4           // j-splits; 1024 j per split, 32 tiles of 32
#define KKSTRIDE 520         // f16 per kk block in LDS: 512 data + 8 pad

#define SPLITS_V 4           // fallback j-splits
#define TILES_PER_SPLIT_V 4

typedef _Float16 f16;
typedef _Float16 f16x8 __attribute__((ext_vector_type(8)));
typedef float    f32x4 __attribute__((ext_vector_type(4)));

__device__ __forceinline__ int iclamp(int v, int lo, int hi) {
    return v < lo ? lo : (v > hi ? hi : v);
}

__device__ __forceinline__ void async_ld16(const void* g, void* l) {
    __builtin_amdgcn_global_load_lds(
        (const __attribute__((address_space(1))) unsigned int*)g,
        (__attribute__((address_space(3))) unsigned int*)l, 16, 0, 0);
}

// ---------------------------------------------------------------------------
// Kernel 1: K-major fp16 hi/lo descriptors + squared norms, coalesced stores.
// D[(n*20 + kk)*4096 + pix][8], kk = k/8, k = d*16 + c (d = dy*3+dx).
// Block: 256 thr handles 4 image rows; grid (16, N_, 2) z=0: t->P+pn, z=1: s.
// ---------------------------------------------------------------------------
__global__ __launch_bounds__(256)
void build_desc_norms_kernel(const float* __restrict__ s,
                             const float* __restrict__ t,
                             f16* __restrict__ Qh, f16* __restrict__ Ql,
                             f16* __restrict__ Ph, f16* __restrict__ Pl,
                             float* __restrict__ pn,
                             float* __restrict__ qn) {
    const int y0  = blockIdx.x * 4;
    const int n   = blockIdx.y;
    const int src = blockIdx.z;                 // 0: t, 1: s
    const float* img = (src ? s : t) + n * (C_ * HW_);
    f16* Dh = src ? Qh : Ph;
    f16* Dl = src ? Ql : Pl;
    float* nrm = src ? qn : pn;

    __shared__ float imgS[C_][8][W_];           // 32 KB: rows y0-1 .. y0+6
    const int tid = threadIdx.x;
    #pragma unroll
    for (int k = 0; k < 32; ++k) {
        const int idx = tid + k * 256;          // 0..8191
        const int x = idx & 63, r = (idx >> 6) & 7, c = idx >> 9;
        const int gy = iclamp(y0 + r - 1, 0, H_ - 1);
        imgS[c][r][x] = img[c * HW_ + gy * W_ + x];
    }
    __syncthreads();

    const int ly = tid >> 6, x = tid & 63;
    const int pix = (y0 + ly) * W_ + x;
    float nacc = 0.f;
    #pragma unroll
    for (int kk = 0; kk < 18; ++kk) {
        const int d  = kk >> 1;
        const int c0 = (kk & 1) * 8;
        const int dy = d / 3, dx = d - dy * 3;  // constant-folded (unrolled)
        const int rr = ly + dy;                 // = clamped (y+dy-1) row
        const int xs = iclamp(x + dx - 1, 0, W_ - 1);
        f16x8 hv, lv;
        #pragma unroll
        for (int cc = 0; cc < 8; ++cc) {
            const float v = imgS[c0 + cc][rr][xs];
            const f16 h = (f16)v;
            hv[cc] = h;
            lv[cc] = (f16)(v - (float)h);
            nacc += v * v;
        }
        const size_t off = ((size_t)(n * 20 + kk) * HW_ + pix) * 8;
        *(f16x8*)&Dh[off] = hv;                 // consecutive pix -> coalesced
        *(f16x8*)&Dl[off] = lv;
    }
    f16x8 z;
    #pragma unroll
    for (int cc = 0; cc < 8; ++cc) z[cc] = (f16)0.f;
    #pragma unroll
    for (int kk = 18; kk < 20; ++kk) {
        const size_t off = ((size_t)(n * 20 + kk) * HW_ + pix) * 8;
        *(f16x8*)&Dh[off] = z;
        *(f16x8*)&Dl[off] = z;
    }
    nrm[n * HW_ + pix] = nacc;
}

// ---------------------------------------------------------------------------
// Kernel 2: MFMA GEMM + fused argmin. 1D grid 512 blocks; block = 4 waves,
// wave 32 i (is=2), block 128 i. j: 32-wide LDS-staged tiles, 32 per split.
// LDS layout per buffer: [kk 0..19][arr h/l][row 0..31][8 f16], stride
// KKSTRIDE=520 f16 per kk (16B pad). Staged by async global_load_lds: wave w
// stages kk = w*5..w*5+4; lane<32 -> h row=lane, lane>=32 -> l row=lane-32.
// mfma_f32_16x16x32_f16: A/B [idx=lane&15][k=quad*8+e]; C col=lane&15,
// row=quad*4+reg (verified layouts).
// ---------------------------------------------------------------------------
__global__ __launch_bounds__(256)
void mfma_nn_kernel(const f16* __restrict__ Qh, const f16* __restrict__ Ql,
                    const f16* __restrict__ Ph, const f16* __restrict__ Pl,
                    const float* __restrict__ pn_g,
                    unsigned long long* __restrict__ partial) {
    const int bid   = blockIdx.x;
    const int split = bid & 3;          // fixed XCD under round-robin
    const int n     = (bid >> 2) & 3;
    const int iblk  = bid >> 4;         // 0..31
    const int tid  = threadIdx.x;
    const int wave = tid >> 6, lane = tid & 63;
    const int m = lane & 15, quad = lane >> 4;
    const int irow0 = iblk * 128 + wave * 32;

    __shared__ f16 B[2][20 * KKSTRIDE];   // 2 x 20800 f16 = 41600 B

    // ---- A fragments, resident (80 VGPR) ----
    f16x8 Ah[2][5], Al[2][5];
    #pragma unroll
    for (int is = 0; is < 2; ++is)
        #pragma unroll
        for (int kc = 0; kc < 5; ++kc) {
            const size_t off = ((size_t)(n * 20 + kc * 4 + quad) * HW_ +
                                irow0 + is * 16 + m) * 8;
            Ah[is][kc] = *(const f16x8*)(Qh + off);
            Al[is][kc] = *(const f16x8*)(Ql + off);
        }

    float    bd[2][4];
    unsigned bj[2][4];
    #pragma unroll
    for (int is = 0; is < 2; ++is)
        #pragma unroll
        for (int rg = 0; rg < 4; ++rg) { bd[is][rg] = 3.0e38f; bj[is][rg] = 0u; }

    const int jsplit0 = split * 1024;
    const int skk  = wave * 5;          // this wave's kk range
    const int sarr = lane >> 5;
    const int srow = lane & 31;
    const f16* sbase = sarr ? Pl : Ph;

    #define STAGE(BUFI, J0)                                                   \
        {   _Pragma("unroll")                                                 \
            for (int u = 0; u < 5; ++u) {                                     \
                const int kk = skk + u;                                       \
                const f16* g = sbase +                                        \
                    ((size_t)(n * 20 + kk) * HW_ + (J0) + srow) * 8;          \
                async_ld16(g, (void*)&B[BUFI][kk * KKSTRIDE + lane * 8]);     \
            }                                                                 \
        }

    STAGE(0, jsplit0)
    asm volatile("s_waitcnt vmcnt(0)" ::: "memory");
    __syncthreads();

    for (int jt = 0; jt < 32; ++jt) {
        const int j0  = jsplit0 + jt * 32;
        const int cur = jt & 1;
        if (jt + 1 < 32) STAGE(cur ^ 1, j0 + 32)   // DMA overlaps compute
        const f16* buf = &B[cur][0];

        #pragma unroll
        for (int js = 0; js < 2; ++js) {
            f32x4 Cf[2];
            Cf[0] = (f32x4){0.f, 0.f, 0.f, 0.f};
            Cf[1] = (f32x4){0.f, 0.f, 0.f, 0.f};
            #pragma unroll
            for (int kc = 0; kc < 5; ++kc) {
                const int kb = (kc * 4 + quad) * KKSTRIDE + (js * 16 + m) * 8;
                const f16x8 bh = *(const f16x8*)&buf[kb];
                const f16x8 bl = *(const f16x8*)&buf[kb + 256];
                #pragma unroll
                for (int is = 0; is < 2; ++is) {
                    Cf[is] = __builtin_amdgcn_mfma_f32_16x16x32_f16(
                        Ah[is][kc], bh, Cf[is], 0, 0, 0);
                    Cf[is] = __builtin_amdgcn_mfma_f32_16x16x32_f16(
                        Al[is][kc], bh, Cf[is], 0, 0, 0);
                    Cf[is] = __builtin_amdgcn_mfma_f32_16x16x32_f16(
                        Ah[is][kc], bl, Cf[is], 0, 0, 0);
                }
            }
            const int jcol = j0 + js * 16 + m;
            const float pnv = pn_g[n * HW_ + jcol];
            #pragma unroll
            for (int is = 0; is < 2; ++is)
                #pragma unroll
                for (int rg = 0; rg < 4; ++rg) {
                    const float d = fmaf(Cf[is][rg], -2.f, pnv);
                    if (d < bd[is][rg]) {        // strict <: earliest j wins
                        bd[is][rg] = d;
                        bj[is][rg] = (unsigned)jcol;
                    }
                }
        }
        asm volatile("s_waitcnt vmcnt(0)" ::: "memory");
        __syncthreads();    // next tile staged AND buf free for overwrite
    }
    #undef STAGE

    // ---- reduce across the 16 m-lanes (same quad = same i rows) ----
    #pragma unroll
    for (int is = 0; is < 2; ++is)
        #pragma unroll
        for (int rg = 0; rg < 4; ++rg) {
            float    d = bd[is][rg];
            unsigned j = bj[is][rg];
            #pragma unroll
            for (int off = 1; off < 16; off <<= 1) {
                const float    od = __shfl_xor(d, off, 64);
                const unsigned oj = __shfl_xor(j, off, 64);
                const bool take = (od < d) || (od == d && oj < j);
                d = take ? od : d;
                j = take ? oj : j;
            }
            if (m == 0) {
                const int i = irow0 + is * 16 + quad * 4 + rg;
                partial[(size_t)(split * N_ + n) * HW_ + i] =
                    ((unsigned long long)j << 32) |
                    (unsigned long long)__float_as_uint(d);
            }
        }
}

// ---------------------------------------------------------------------------
// Kernel 3: reduce splits, add qn, decode, write outputs (float32)
// ---------------------------------------------------------------------------
__global__ __launch_bounds__(256)
void finalize_mfma_kernel(const unsigned long long* __restrict__ partial,
                          const float* __restrict__ qn_g,
                          float* __restrict__ out) {
    const int id  = blockIdx.x * 256 + threadIdx.x;   // 0..16383
    const int n   = id >> 12;
    const int pix = id & 4095;
    float    bd = 3.0e38f;
    unsigned bj = 0u;
    #pragma unroll
    for (int sp = 0; sp < SPLITS_M; ++sp) {
        const unsigned long long v = partial[(size_t)(sp * N_ + n) * HW_ + pix];
        const float    d = __uint_as_float((unsigned)(v & 0xffffffffull));
        const unsigned j = (unsigned)(v >> 32);
        const bool take = (d < bd) || (d == bd && j < bj);
        bd = take ? d : bd;
        bj = take ? j : bj;
    }
    out[n * 2 * HW_ + pix]            = (float)(bj >> 6);          // idy
    out[n * 2 * HW_ + HW_ + pix]      = (float)(bj & 63);          // idx_x
    out[N_ * 2 * HW_ + n * HW_ + pix] = bd + qn_g[n * HW_ + pix];  // nnd
}

// ===========================================================================
// Fallback path (fp32 vector) + helpers — unchanged
// ===========================================================================
__global__ __launch_bounds__(256)
void prep_norms_kernel(const float* __restrict__ s,
                       const float* __restrict__ t,
                       float* __restrict__ pn,
                       float* __restrict__ qn) {
    const int gid   = blockIdx.x * 256 + threadIdx.x;
    const int which = gid >> 14;
    const int id    = gid & 16383;
    const int n     = id >> 12;
    const int pix   = id & 4095;
    const int y = pix >> 6, x = pix & 63;
    const float* base = (which ? s : t) + n * (C_ * HW_);
    float acc = 0.f;
    for (int c = 0; c < C_; ++c) {
        const float* bc = base + c * HW_;
        #pragma unroll
        for (int dy = 0; dy < 3; ++dy) {
            const float* br = bc + iclamp(y + dy - 1, 0, H_ - 1) * W_;
            #pragma unroll
            for (int dx = 0; dx < 3; ++dx) {
                float v = br[iclamp(x + dx - 1, 0, W_ - 1)];
                acc += v * v;
            }
        }
    }
    (which ? qn : pn)[id] = acc;
}

__global__ __launch_bounds__(256)
void patchmatch_main_kernel(const float* __restrict__ s,
                            const float* __restrict__ t,
                            const float* __restrict__ pn_g,
                            const float* __restrict__ qn_g,
                            unsigned long long* __restrict__ partial) {
    const int yq    = blockIdx.x;
    const int n     = blockIdx.y;
    const int split = blockIdx.z;
    const int tid  = threadIdx.x;
    const int tx   = tid & 15;
    const int ty   = tid >> 4;
    const int i0   = ty * 4;
    const int jrow = tx >> 2;
    const int jx0  = (tx & 3) * 16;

    __shared__ float qS[C_][3][68];
    __shared__ float tS[C_][6][68];
    __shared__ float qnS[W_];

    const float* sb = s + n * (C_ * HW_);
    const float* tb = t + n * (C_ * HW_);

    #pragma unroll
    for (int k = 0; k < 3; ++k) {
        const int id = tid + k * 256;
        const int sg = id & 15;
        const int c  = (id >> 4) & 15;
        const int r  = id >> 8;
        const int gr = iclamp(yq + r - 1, 0, H_ - 1);
        const float4 v = *(const float4*)&sb[c * HW_ + gr * W_ + sg * 4];
        float* dst = &qS[c][r][1 + sg * 4];
        dst[0] = v.x; dst[1] = v.y; dst[2] = v.z; dst[3] = v.w;
    }
    if (tid < 48) {
        const int c  = tid & 15;
        const int r  = tid >> 4;
        const int gr = iclamp(yq + r - 1, 0, H_ - 1);
        qS[c][r][0]  = sb[c * HW_ + gr * W_];
        qS[c][r][65] = sb[c * HW_ + gr * W_ + 63];
    }
    if (tid < W_) qnS[tid] = qn_g[n * HW_ + yq * W_ + tid];

    unsigned long long best[4] = {~0ull, ~0ull, ~0ull, ~0ull};

    for (int ytl = 0; ytl < TILES_PER_SPLIT_V; ++ytl) {
        const int yt = split * TILES_PER_SPLIT_V + ytl;
        __syncthreads();
        #pragma unroll
        for (int k = 0; k < 6; ++k) {
            const int id = tid + k * 256;
            const int sg = id & 15;
            const int c  = (id >> 4) & 15;
            const int r  = id >> 8;
            const int gr = iclamp(4 * yt + r - 1, 0, H_ - 1);
            const float4 v = *(const float4*)&tb[c * HW_ + gr * W_ + sg * 4];
            float* dst = &tS[c][r][1 + sg * 4];
            dst[0] = v.x; dst[1] = v.y; dst[2] = v.z; dst[3] = v.w;
        }
        if (tid < 96) {
            const int c  = tid & 15;
            const int r  = tid >> 4;
            const int gr = iclamp(4 * yt + r - 1, 0, H_ - 1);
            tS[c][r][0]  = tb[c * HW_ + gr * W_];
            tS[c][r][65] = tb[c * HW_ + gr * W_ + 63];
        }
        __syncthreads();

        float acc[4][16];
        #pragma unroll
        for (int a = 0; a < 4; ++a)
            #pragma unroll
            for (int b = 0; b < 16; ++b) acc[a][b] = 0.f;

        for (int c = 0; c < C_; ++c) {
            #pragma unroll
            for (int dy = 0; dy < 3; ++dy) {
                float qv[6], tv[18];
                *(float4*)&qv[0] = *(const float4*)&qS[c][dy][i0];
                *(float2*)&qv[4] = *(const float2*)&qS[c][dy][i0 + 4];
                const float* trow = &tS[c][jrow + dy][jx0];
                *(float4*)&tv[0]  = *(const float4*)&trow[0];
                *(float4*)&tv[4]  = *(const float4*)&trow[4];
                *(float4*)&tv[8]  = *(const float4*)&trow[8];
                *(float4*)&tv[12] = *(const float4*)&trow[12];
                *(float2*)&tv[16] = *(const float2*)&trow[16];
                #pragma unroll
                for (int dx = 0; dx < 3; ++dx)
                    #pragma unroll
                    for (int a = 0; a < 4; ++a)
                        #pragma unroll
                        for (int b = 0; b < 16; ++b)
                            acc[a][b] += qv[a + dx] * tv[b + dx];
            }
        }

        const int jbase = yt * 256 + jrow * W_ + jx0;
        float pnv[16];
        const float* png = &pn_g[n * HW_ + jbase];
        *(float4*)&pnv[0]  = *(const float4*)&png[0];
        *(float4*)&pnv[4]  = *(const float4*)&png[4];
        *(float4*)&pnv[8]  = *(const float4*)&png[8];
        *(float4*)&pnv[12] = *(const float4*)&png[12];
        #pragma unroll
        for (int a = 0; a < 4; ++a) {
            const float qn = qnS[i0 + a];
            #pragma unroll
            for (int b = 0; b < 16; ++b) {
                const float d2 = qn + pnv[b] - 2.f * acc[a][b];
                unsigned long long cand =
                    ((unsigned long long)__float_as_uint(d2) << 32) |
                    (unsigned)(jbase + b);
                best[a] = cand < best[a] ? cand : best[a];
            }
        }
    }

    #pragma unroll
    for (int a = 0; a < 4; ++a) {
        unsigned long long v = best[a];
        #pragma unroll
        for (int mm = 8; mm >= 1; mm >>= 1) {
            unsigned long long o = __shfl_xor(v, mm, 64);
            v = o < v ? o : v;
        }
        best[a] = v;
    }
    if (tx == 0) {
        #pragma unroll
        for (int a = 0; a < 4; ++a)
            partial[((split * N_ + n) * HW_) + yq * W_ + i0 + a] = best[a];
    }
}

__global__ __launch_bounds__(256)
void finalize_kernel(const unsigned long long* __restrict__ partial,
                     float* __restrict__ out) {
    const int id  = blockIdx.x * 256 + threadIdx.x;
    const int n   = id >> 12;
    const int pix = id & 4095;
    unsigned long long best = ~0ull;
    #pragma unroll
    for (int sp = 0; sp < SPLITS_V; ++sp) {
        unsigned long long v = partial[(sp * N_ + n) * HW_ + pix];
        best = v < best ? v : best;
    }
    const unsigned j = (unsigned)(best & 0xffffffffu);
    const float d2 = __uint_as_float((unsigned)(best >> 32));
    out[n * 2 * HW_ + pix]            = (float)(j >> 6);
    out[n * 2 * HW_ + HW_ + pix]      = (float)(j & 63);
    out[N_ * 2 * HW_ + n * HW_ + pix] = d2;
}

__global__ __launch_bounds__(256)
void patchmatch_mono_kernel(const float* __restrict__ s,
                            const float* __restrict__ t,
                            float* __restrict__ out) {
    const int yq  = blockIdx.x;
    const int n   = blockIdx.y;
    const int tid = threadIdx.x;
    const int tx  = tid & 15;
    const int ty  = tid >> 4;
    const int i0  = ty * 4;
    const int jrow = tx >> 3;
    const int jx0  = (tx & 7) * 8;

    __shared__ float qS[C_][3][68];
    __shared__ float tS[C_][4][68];
    __shared__ float pnS[HW_];
    __shared__ float qnS[W_];

    const float* sb = s + n * (C_ * HW_);
    const float* tb = t + n * (C_ * HW_);

    for (int jj = tid; jj < HW_; jj += 256) {
        const int y = jj >> 6, x = jj & 63;
        float acc = 0.f;
        for (int c = 0; c < C_; ++c) {
            const float* tc = tb + c * HW_;
            #pragma unroll
            for (int dy = 0; dy < 3; ++dy) {
                const float* tr = tc + iclamp(y + dy - 1, 0, H_ - 1) * W_;
                #pragma unroll
                for (int dx = 0; dx < 3; ++dx) {
                    float v = tr[iclamp(x + dx - 1, 0, W_ - 1)];
                    acc += v * v;
                }
            }
        }
        pnS[jj] = acc;
    }
    for (int idx = tid; idx < C_ * 3 * 66; idx += 256) {
        const int c   = idx / (3 * 66);
        const int rem = idx - c * (3 * 66);
        const int rr  = rem / 66;
        const int xi  = rem - rr * 66;
        qS[c][rr][xi] = sb[c * HW_ + iclamp(yq + rr - 1, 0, H_ - 1) * W_ +
                           iclamp(xi - 1, 0, W_ - 1)];
    }
    __syncthreads();
    if (tid < W_) {
        float acc = 0.f;
        for (int c = 0; c < C_; ++c)
            #pragma unroll
            for (int dy = 0; dy < 3; ++dy)
                #pragma unroll
                for (int dx = 0; dx < 3; ++dx) {
                    float v = qS[c][dy][tid + dx];
                    acc += v * v;
                }
        qnS[tid] = acc;
    }

    unsigned long long best[4] = {~0ull, ~0ull, ~0ull, ~0ull};
    for (int yt = 0; yt < 32; ++yt) {
        __syncthreads();
        for (int idx = tid; idx < C_ * 4 * 66; idx += 256) {
            const int c   = idx / (4 * 66);
            const int rem = idx - c * (4 * 66);
            const int rr  = rem / 66;
            const int xi  = rem - rr * 66;
            tS[c][rr][xi] = tb[c * HW_ + iclamp(2 * yt + rr - 1, 0, H_ - 1) * W_ +
                               iclamp(xi - 1, 0, W_ - 1)];
        }
        __syncthreads();

        float acc[4][8];
        #pragma unroll
        for (int a = 0; a < 4; ++a)
            #pragma unroll
            for (int b = 0; b < 8; ++b) acc[a][b] = 0.f;

        for (int c = 0; c < C_; ++c) {
            #pragma unroll
            for (int dy = 0; dy < 3; ++dy) {
                float qv[8], tv[12];
                *(float4*)&qv[0] = *(const float4*)&qS[c][dy][i0];
                *(float4*)&qv[4] = *(const float4*)&qS[c][dy][i0 + 4];
                const float* trow = &tS[c][jrow + dy][jx0];
                *(float4*)&tv[0] = *(const float4*)&trow[0];
                *(float4*)&tv[4] = *(const float4*)&trow[4];
                *(float4*)&tv[8] = *(const float4*)&trow[8];
                #pragma unroll
                for (int dx = 0; dx < 3; ++dx)
                    #pragma unroll
                    for (int a = 0; a < 4; ++a)
                        #pragma unroll
                        for (int b = 0; b < 8; ++b)
                            acc[a][b] += qv[a + dx] * tv[b + dx];
            }
        }
        const int rbase = (2 * yt + jrow) * W_ + jx0;
        #pragma unroll
        for (int a = 0; a < 4; ++a) {
            const float qn = qnS[i0 + a];
            #pragma unroll
            for (int b = 0; b < 8; ++b) {
                const int j = rbase + b;
                const float d2 = qn + pnS[j] - 2.f * acc[a][b];
                unsigned long long cand =
                    ((unsigned long long)__float_as_uint(d2) << 32) | (unsigned)j;
                best[a] = cand < best[a] ? cand : best[a];
            }
        }
    }
    #pragma unroll
    for (int a = 0; a < 4; ++a) {
        unsigned long long v = best[a];
        #pragma unroll
        for (int mm = 8; mm >= 1; mm >>= 1) {
            unsigned long long o = __shfl_xor(v, mm, 64);
            v = o < v ? o : v;
        }
        best[a] = v;
    }
    if (tx == 0) {
        #pragma unroll
        for (int a = 0; a < 4; ++a) {
            const int x = i0 + a;
            const unsigned j = (unsigned)(best[a] & 0xffffffffu);
            const float d2 = __uint_as_float((unsigned)(best[a] >> 32));
            const int pix = yq * W_ + x;
            out[n * 2 * HW_ + pix]            = (float)(j >> 6);
            out[n * 2 * HW_ + HW_ + pix]      = (float)(j & 63);
            out[N_ * 2 * HW_ + n * HW_ + pix] = d2;
        }
    }
}

// ===========================================================================
extern "C" void kernel_launch(void* const* d_in, const int* in_sizes, int n_in,
                              void* d_out, int out_size, void* d_ws, size_t ws_size,
                              hipStream_t stream) {
    const float* s = (const float*)d_in[0];
    const float* t = (const float*)d_in[1];
    float* out = (float*)d_out;

    // MFMA ws layout:
    //   pn [4][4096] f32 | qn [4][4096] f32 | partial [4][4][4096] u64 |
    //   Qh | Ql | Ph | Pl   each K-major [4][20][4096][8] f16 (5.24 MB)
    const size_t norm_b  = (size_t)N_ * HW_ * 4;
    const size_t part_b  = (size_t)SPLITS_M * N_ * HW_ * 8;
    const size_t desc_b  = (size_t)N_ * HW_ * K_ * 2;
    const size_t need_m  = 2 * norm_b + part_b + 4 * desc_b;     // ~21.5 MB

    if (ws_size >= need_m) {
        char* w = (char*)d_ws;
        float* pn = (float*)w;                       w += norm_b;
        float* qn = (float*)w;                       w += norm_b;
        unsigned long long* partial = (unsigned long long*)w; w += part_b;
        f16* Qh = (f16*)w;  w += desc_b;
        f16* Ql = (f16*)w;  w += desc_b;
        f16* Ph = (f16*)w;  w += desc_b;
        f16* Pl = (f16*)w;

        build_desc_norms_kernel<<<dim3(16, N_, 2), 256, 0, stream>>>(
            s, t, Qh, Ql, Ph, Pl, pn, qn);
        mfma_nn_kernel<<<512, 256, 0, stream>>>(Qh, Ql, Ph, Pl, pn, partial);
        finalize_mfma_kernel<<<64, 256, 0, stream>>>(partial, qn, out);
        return;
    }

    // Fallback: fp32 vector path
    const size_t need_v = 2 * norm_b + (size_t)SPLITS_V * N_ * HW_ * 8;
    if (ws_size >= need_v) {
        float* pn = (float*)d_ws;
        float* qn = pn + N_ * HW_;
        unsigned long long* partial =
            (unsigned long long*)((char*)d_ws + 2 * norm_b);
        prep_norms_kernel<<<128, 256, 0, stream>>>(s, t, pn, qn);
        dim3 grid(H_, N_, SPLITS_V);
        patchmatch_main_kernel<<<grid, 256, 0, stream>>>(s, t, pn, qn, partial);
        finalize_kernel<<<64, 256, 0, stream>>>(partial, out);
        return;
    }

    dim3 grid(H_, N_);
    patchmatch_mono_kernel<<<grid, 256, 0, stream>>>(s, t, out);
}

// Round 12
// 124.819 us; speedup vs baseline: 1.4823x; 1.0609x over previous
//
#include <hip/hip_runtime.h>

// PatchMatch brute-force NN on MI355X.
// s,t (4,16,64,64) fp32; descriptor = 3x3 replicate-padded patch, K=144 (pad 160).
// d2(i,j) = qn_i - 2*cross(i,j) + pn_j; argmin_j (ties -> smallest j).
// Outputs (flat, ALL FLOAT32): nnf (4,2,64,64) then nnd (4,1,64,64).
//
// R12 vs R11 (total 132us; mfma 62us @ MfmaUtil 43%, ~50% per-tile barrier
// drain; build_desc ~30us on 128 blocks):
//  - mfma: triple-buffered B in THREE distinct __shared__ arrays, jt loop
//    unrolled x3, raw `s_waitcnt vmcnt(5)` + `s_barrier` per tile (AITER
//    pattern: prefetch DMA stays in flight across the barrier).
//  - KKSTRIDE 520->528 (quad stride === 8 dw mod 32, kills conflict tax);
//    pn staged to LDS once per split.
//  - build_desc: 512 blocks, 1 row each, wave-per-kk-group -> 1KB coalesced
//    wavefront stores; norms via cross-wave LDS sum.

#define N_  4
#define C_  16
#define H_  64
#define W_  64
#define HW_ 4096
#define K_  160              // 144 real + 16 zero-pad; 20 chunks of 8
#define SPLITS_M 4           // j-splits; 1024 j per split, 32 tiles of 32
#define KKSTRIDE 528         // f16 per kk block in LDS: 512 data + 16 pad

#define SPLITS_V 4           // fallback j-splits
#define TILES_PER_SPLIT_V 4

typedef _Float16 f16;
typedef _Float16 f16x8 __attribute__((ext_vector_type(8)));
typedef float    f32x4 __attribute__((ext_vector_type(4)));

__device__ __forceinline__ int iclamp(int v, int lo, int hi) {
    return v < lo ? lo : (v > hi ? hi : v);
}

__device__ __forceinline__ void async_ld16(const void* g, void* l) {
    __builtin_amdgcn_global_load_lds(
        (const __attribute__((address_space(1))) unsigned int*)g,
        (__attribute__((address_space(3))) unsigned int*)l, 16, 0, 0);
}

// ---------------------------------------------------------------------------
// Kernel 1: K-major fp16 hi/lo descriptors + squared norms.
// D[(n*20 + kk)*4096 + pix][8], kk = k/8, k = d*16 + c (d = dy*3+dx).
// One block per image row; wave q handles kk = q*5..q*5+4 for all 64 px ->
// every store is a 1KB coalesced wavefront store. grid (64, N_, 2).
// ---------------------------------------------------------------------------
__global__ __launch_bounds__(256)
void build_desc_norms_kernel(const float* __restrict__ s,
                             const float* __restrict__ t,
                             f16* __restrict__ Qh, f16* __restrict__ Ql,
                             f16* __restrict__ Ph, f16* __restrict__ Pl,
                             float* __restrict__ pn,
                             float* __restrict__ qn) {
    const int y0  = blockIdx.x;                 // image row
    const int n   = blockIdx.y;
    const int src = blockIdx.z;                 // 0: t, 1: s
    const float* img = (src ? s : t) + n * (C_ * HW_);
    f16* Dh = src ? Qh : Ph;
    f16* Dl = src ? Ql : Pl;
    float* nrm = src ? qn : pn;

    __shared__ float imgS[3][C_][W_];           // 12 KB: rows y0-1..y0+1
    __shared__ float nS[4][W_];
    const int tid = threadIdx.x;
    #pragma unroll
    for (int k = 0; k < 12; ++k) {
        const int idx = tid + k * 256;          // 0..3071
        const int x = idx & 63, c = (idx >> 6) & 15, r = idx >> 10;  // r 0..2
        const int gy = iclamp(y0 + r - 1, 0, H_ - 1);
        imgS[r][c][x] = img[c * HW_ + gy * W_ + x];
    }
    __syncthreads();

    const int q = tid >> 6, x = tid & 63;       // wave, lane(=pixel x)
    const int pix = y0 * W_ + x;
    float nacc = 0.f;
    #pragma unroll
    for (int u = 0; u < 5; ++u) {
        const int kk = q * 5 + u;               // 0..19
        f16x8 hv, lv;
        if (kk < 18) {
            const int d  = kk >> 1;             // 0..8
            const int c0 = (kk & 1) * 8;
            const int dy = (d * 11) >> 5;       // d/3 for d in [0,8]
            const int dx = d - dy * 3;
            const int xs = iclamp(x + dx - 1, 0, W_ - 1);
            #pragma unroll
            for (int cc = 0; cc < 8; ++cc) {
                const float v = imgS[dy][c0 + cc][xs];
                const f16 h = (f16)v;
                hv[cc] = h;
                lv[cc] = (f16)(v - (float)h);
                nacc += v * v;
            }
        } else {
            #pragma unroll
            for (int cc = 0; cc < 8; ++cc) { hv[cc] = (f16)0.f; lv[cc] = (f16)0.f; }
        }
        const size_t off = ((size_t)(n * 20 + kk) * HW_ + pix) * 8;
        *(f16x8*)&Dh[off] = hv;                 // 64 lanes x 16B contiguous
        *(f16x8*)&Dl[off] = lv;
    }
    nS[q][x] = nacc;
    __syncthreads();
    if (tid < W_)
        nrm[n * HW_ + pix] = nS[0][tid] + nS[1][tid] + nS[2][tid] + nS[3][tid];
}

// ---------------------------------------------------------------------------
// Kernel 2: MFMA GEMM + fused argmin. 1D grid 512 blocks (split=bid&3 for
// XCD affinity); block = 4 waves, wave 32 i (is=2), block 128 i.
// j: 32-wide tiles x32/split, TRIPLE-buffered async DMA staging, raw
// s_waitcnt vmcnt(5)+s_barrier per tile (prefetch in flight across barrier).
// LDS per buffer: [kk 0..19][h(32 rows)|l(32 rows)][8 f16], KKSTRIDE=528.
// mfma_f32_16x16x32_f16: A/B [idx=lane&15][k=quad*8+e]; C col=lane&15,
// row=quad*4+reg (verified layouts).
// ---------------------------------------------------------------------------
__global__ __launch_bounds__(256)
void mfma_nn_kernel(const f16* __restrict__ Qh, const f16* __restrict__ Ql,
                    const f16* __restrict__ Ph, const f16* __restrict__ Pl,
                    const float* __restrict__ pn_g,
                    unsigned long long* __restrict__ partial) {
    const int bid   = blockIdx.x;
    const int split = bid & 3;          // fixed XCD under round-robin
    const int n     = (bid >> 2) & 3;
    const int iblk  = bid >> 4;         // 0..31
    const int tid  = threadIdx.x;
    const int wave = tid >> 6, lane = tid & 63;
    const int m = lane & 15, quad = lane >> 4;
    const int irow0 = iblk * 128 + wave * 32;

    __shared__ f16 B0[20 * KKSTRIDE];   // 21120 B each
    __shared__ f16 B1[20 * KKSTRIDE];
    __shared__ f16 B2[20 * KKSTRIDE];
    __shared__ float pnS[1024];         // this split's pn

    // ---- A fragments, resident (80 VGPR) ----
    f16x8 Ah[2][5], Al[2][5];
    #pragma unroll
    for (int is = 0; is < 2; ++is)
        #pragma unroll
        for (int kc = 0; kc < 5; ++kc) {
            const size_t off = ((size_t)(n * 20 + kc * 4 + quad) * HW_ +
                                irow0 + is * 16 + m) * 8;
            Ah[is][kc] = *(const f16x8*)(Qh + off);
            Al[is][kc] = *(const f16x8*)(Ql + off);
        }

    const int jsplit0 = split * 1024;
    #pragma unroll
    for (int k = 0; k < 4; ++k)
        pnS[tid + k * 256] = pn_g[n * HW_ + jsplit0 + tid + k * 256];

    float    bd[2][4];
    unsigned bj[2][4];
    #pragma unroll
    for (int is = 0; is < 2; ++is)
        #pragma unroll
        for (int rg = 0; rg < 4; ++rg) { bd[is][rg] = 3.0e38f; bj[is][rg] = 0u; }

    const int skk  = wave * 5;          // this wave's kk range
    const int sarr = lane >> 5;
    const int srow = lane & 31;
    const f16* sbase = sarr ? Pl : Ph;

    #define STAGE(BUF, T)                                                     \
        {   _Pragma("unroll")                                                 \
            for (int u = 0; u < 5; ++u) {                                     \
                const int kk = skk + u;                                       \
                const f16* g = sbase + ((size_t)(n * 20 + kk) * HW_ +         \
                                        jsplit0 + (T) * 32 + srow) * 8;       \
                async_ld16(g, (void*)&BUF[kk * KKSTRIDE + lane * 8]);         \
            }                                                                 \
        }

    #define COMPUTE(BUF, T)                                                   \
        {   _Pragma("unroll")                                                 \
            for (int js = 0; js < 2; ++js) {                                  \
                f32x4 Cf[2];                                                  \
                Cf[0] = (f32x4){0.f, 0.f, 0.f, 0.f};                          \
                Cf[1] = (f32x4){0.f, 0.f, 0.f, 0.f};                          \
                _Pragma("unroll")                                             \
                for (int kc = 0; kc < 5; ++kc) {                              \
                    const int kb = (kc * 4 + quad) * KKSTRIDE +               \
                                   (js * 16 + m) * 8;                         \
                    const f16x8 bh = *(const f16x8*)&BUF[kb];                 \
                    const f16x8 bl = *(const f16x8*)&BUF[kb + 256];           \
                    _Pragma("unroll")                                         \
                    for (int is = 0; is < 2; ++is) {                          \
                        Cf[is] = __builtin_amdgcn_mfma_f32_16x16x32_f16(      \
                            Ah[is][kc], bh, Cf[is], 0, 0, 0);                 \
                        Cf[is] = __builtin_amdgcn_mfma_f32_16x16x32_f16(      \
                            Al[is][kc], bh, Cf[is], 0, 0, 0);                 \
                        Cf[is] = __builtin_amdgcn_mfma_f32_16x16x32_f16(      \
                            Ah[is][kc], bl, Cf[is], 0, 0, 0);                 \
                    }                                                         \
                }                                                             \
                const int jloc = (T) * 32 + js * 16 + m;                      \
                const float pnv = pnS[jloc];                                  \
                _Pragma("unroll")                                             \
                for (int is = 0; is < 2; ++is)                                \
                    _Pragma("unroll")                                         \
                    for (int rg = 0; rg < 4; ++rg) {                          \
                        const float d = fmaf(Cf[is][rg], -2.f, pnv);          \
                        if (d < bd[is][rg]) {                                 \
                            bd[is][rg] = d;                                   \
                            bj[is][rg] = (unsigned)jloc;                      \
                        }                                                     \
                    }                                                         \
            }                                                                 \
        }

    STAGE(B0, 0)
    STAGE(B1, 1)
    __syncthreads();    // pnS + first two stages visible (one-time full drain)

    for (int g = 0; g < 10; ++g) {
        const int t = g * 3;
        asm volatile("s_waitcnt vmcnt(5)" ::: "memory");
        asm volatile("s_barrier" ::: "memory");
        STAGE(B2, t + 2)
        COMPUTE(B0, t)
        asm volatile("s_waitcnt vmcnt(5)" ::: "memory");
        asm volatile("s_barrier" ::: "memory");
        STAGE(B0, t + 3)
        COMPUTE(B1, t + 1)
        asm volatile("s_waitcnt vmcnt(5)" ::: "memory");
        asm volatile("s_barrier" ::: "memory");
        STAGE(B1, t + 4)
        COMPUTE(B2, t + 2)
    }
    asm volatile("s_waitcnt vmcnt(5)" ::: "memory");
    asm volatile("s_barrier" ::: "memory");
    COMPUTE(B0, 30)
    asm volatile("s_waitcnt vmcnt(0)" ::: "memory");
    asm volatile("s_barrier" ::: "memory");
    COMPUTE(B1, 31)
    #undef STAGE
    #undef COMPUTE

    // ---- reduce across the 16 m-lanes (same quad = same i rows) ----
    #pragma unroll
    for (int is = 0; is < 2; ++is)
        #pragma unroll
        for (int rg = 0; rg < 4; ++rg) {
            float    d = bd[is][rg];
            unsigned j = (unsigned)jsplit0 + bj[is][rg];
            #pragma unroll
            for (int off = 1; off < 16; off <<= 1) {
                const float    od = __shfl_xor(d, off, 64);
                const unsigned oj = __shfl_xor(j, off, 64);
                const bool take = (od < d) || (od == d && oj < j);
                d = take ? od : d;
                j = take ? oj : j;
            }
            if (m == 0) {
                const int i = irow0 + is * 16 + quad * 4 + rg;
                partial[(size_t)(split * N_ + n) * HW_ + i] =
                    ((unsigned long long)j << 32) |
                    (unsigned long long)__float_as_uint(d);
            }
        }
}

// ---------------------------------------------------------------------------
// Kernel 3: reduce splits, add qn, decode, write outputs (float32)
// ---------------------------------------------------------------------------
__global__ __launch_bounds__(256)
void finalize_mfma_kernel(const unsigned long long* __restrict__ partial,
                          const float* __restrict__ qn_g,
                          float* __restrict__ out) {
    const int id  = blockIdx.x * 256 + threadIdx.x;   // 0..16383
    const int n   = id >> 12;
    const int pix = id & 4095;
    float    bd = 3.0e38f;
    unsigned bj = 0u;
    #pragma unroll
    for (int sp = 0; sp < SPLITS_M; ++sp) {
        const unsigned long long v = partial[(size_t)(sp * N_ + n) * HW_ + pix];
        const float    d = __uint_as_float((unsigned)(v & 0xffffffffull));
        const unsigned j = (unsigned)(v >> 32);
        const bool take = (d < bd) || (d == bd && j < bj);
        bd = take ? d : bd;
        bj = take ? j : bj;
    }
    out[n * 2 * HW_ + pix]            = (float)(bj >> 6);          // idy
    out[n * 2 * HW_ + HW_ + pix]      = (float)(bj & 63);          // idx_x
    out[N_ * 2 * HW_ + n * HW_ + pix] = bd + qn_g[n * HW_ + pix];  // nnd
}

// ===========================================================================
// Fallback path (fp32 vector) + helpers — unchanged
// ===========================================================================
__global__ __launch_bounds__(256)
void prep_norms_kernel(const float* __restrict__ s,
                       const float* __restrict__ t,
                       float* __restrict__ pn,
                       float* __restrict__ qn) {
    const int gid   = blockIdx.x * 256 + threadIdx.x;
    const int which = gid >> 14;
    const int id    = gid & 16383;
    const int n     = id >> 12;
    const int pix   = id & 4095;
    const int y = pix >> 6, x = pix & 63;
    const float* base = (which ? s : t) + n * (C_ * HW_);
    float acc = 0.f;
    for (int c = 0; c < C_; ++c) {
        const float* bc = base + c * HW_;
        #pragma unroll
        for (int dy = 0; dy < 3; ++dy) {
            const float* br = bc + iclamp(y + dy - 1, 0, H_ - 1) * W_;
            #pragma unroll
            for (int dx = 0; dx < 3; ++dx) {
                float v = br[iclamp(x + dx - 1, 0, W_ - 1)];
                acc += v * v;
            }
        }
    }
    (which ? qn : pn)[id] = acc;
}

__global__ __launch_bounds__(256)
void patchmatch_main_kernel(const float* __restrict__ s,
                            const float* __restrict__ t,
                            const float* __restrict__ pn_g,
                            const float* __restrict__ qn_g,
                            unsigned long long* __restrict__ partial) {
    const int yq    = blockIdx.x;
    const int n     = blockIdx.y;
    const int split = blockIdx.z;
    const int tid  = threadIdx.x;
    const int tx   = tid & 15;
    const int ty   = tid >> 4;
    const int i0   = ty * 4;
    const int jrow = tx >> 2;
    const int jx0  = (tx & 3) * 16;

    __shared__ float qS[C_][3][68];
    __shared__ float tS[C_][6][68];
    __shared__ float qnS[W_];

    const float* sb = s + n * (C_ * HW_);
    const float* tb = t + n * (C_ * HW_);

    #pragma unroll
    for (int k = 0; k < 3; ++k) {
        const int id = tid + k * 256;
        const int sg = id & 15;
        const int c  = (id >> 4) & 15;
        const int r  = id >> 8;
        const int gr = iclamp(yq + r - 1, 0, H_ - 1);
        const float4 v = *(const float4*)&sb[c * HW_ + gr * W_ + sg * 4];
        float* dst = &qS[c][r][1 + sg * 4];
        dst[0] = v.x; dst[1] = v.y; dst[2] = v.z; dst[3] = v.w;
    }
    if (tid < 48) {
        const int c  = tid & 15;
        const int r  = tid >> 4;
        const int gr = iclamp(yq + r - 1, 0, H_ - 1);
        qS[c][r][0]  = sb[c * HW_ + gr * W_];
        qS[c][r][65] = sb[c * HW_ + gr * W_ + 63];
    }
    if (tid < W_) qnS[tid] = qn_g[n * HW_ + yq * W_ + tid];

    unsigned long long best[4] = {~0ull, ~0ull, ~0ull, ~0ull};

    for (int ytl = 0; ytl < TILES_PER_SPLIT_V; ++ytl) {
        const int yt = split * TILES_PER_SPLIT_V + ytl;
        __syncthreads();
        #pragma unroll
        for (int k = 0; k < 6; ++k) {
            const int id = tid + k * 256;
            const int sg = id & 15;
            const int c  = (id >> 4) & 15;
            const int r  = id >> 8;
            const int gr = iclamp(4 * yt + r - 1, 0, H_ - 1);
            const float4 v = *(const float4*)&tb[c * HW_ + gr * W_ + sg * 4];
            float* dst = &tS[c][r][1 + sg * 4];
            dst[0] = v.x; dst[1] = v.y; dst[2] = v.z; dst[3] = v.w;
        }
        if (tid < 96) {
            const int c  = tid & 15;
            const int r  = tid >> 4;
            const int gr = iclamp(4 * yt + r - 1, 0, H_ - 1);
            tS[c][r][0]  = tb[c * HW_ + gr * W_];
            tS[c][r][65] = tb[c * HW_ + gr * W_ + 63];
        }
        __syncthreads();

        float acc[4][16];
        #pragma unroll
        for (int a = 0; a < 4; ++a)
            #pragma unroll
            for (int b = 0; b < 16; ++b) acc[a][b] = 0.f;

        for (int c = 0; c < C_; ++c) {
            #pragma unroll
            for (int dy = 0; dy < 3; ++dy) {
                float qv[6], tv[18];
                *(float4*)&qv[0] = *(const float4*)&qS[c][dy][i0];
                *(float2*)&qv[4] = *(const float2*)&qS[c][dy][i0 + 4];
                const float* trow = &tS[c][jrow + dy][jx0];
                *(float4*)&tv[0]  = *(const float4*)&trow[0];
                *(float4*)&tv[4]  = *(const float4*)&trow[4];
                *(float4*)&tv[8]  = *(const float4*)&trow[8];
                *(float4*)&tv[12] = *(const float4*)&trow[12];
                *(float2*)&tv[16] = *(const float2*)&trow[16];
                #pragma unroll
                for (int dx = 0; dx < 3; ++dx)
                    #pragma unroll
                    for (int a = 0; a < 4; ++a)
                        #pragma unroll
                        for (int b = 0; b < 16; ++b)
                            acc[a][b] += qv[a + dx] * tv[b + dx];
            }
        }

        const int jbase = yt * 256 + jrow * W_ + jx0;
        float pnv[16];
        const float* png = &pn_g[n * HW_ + jbase];
        *(float4*)&pnv[0]  = *(const float4*)&png[0];
        *(float4*)&pnv[4]  = *(const float4*)&png[4];
        *(float4*)&pnv[8]  = *(const float4*)&png[8];
        *(float4*)&pnv[12] = *(const float4*)&png[12];
        #pragma unroll
        for (int a = 0; a < 4; ++a) {
            const float qn = qnS[i0 + a];
            #pragma unroll
            for (int b = 0; b < 16; ++b) {
                const float d2 = qn + pnv[b] - 2.f * acc[a][b];
                unsigned long long cand =
                    ((unsigned long long)__float_as_uint(d2) << 32) |
                    (unsigned)(jbase + b);
                best[a] = cand < best[a] ? cand : best[a];
            }
        }
    }

    #pragma unroll
    for (int a = 0; a < 4; ++a) {
        unsigned long long v = best[a];
        #pragma unroll
        for (int mm = 8; mm >= 1; mm >>= 1) {
            unsigned long long o = __shfl_xor(v, mm, 64);
            v = o < v ? o : v;
        }
        best[a] = v;
    }
    if (tx == 0) {
        #pragma unroll
        for (int a = 0; a < 4; ++a)
            partial[((split * N_ + n) * HW_) + yq * W_ + i0 + a] = best[a];
    }
}

__global__ __launch_bounds__(256)
void finalize_kernel(const unsigned long long* __restrict__ partial,
                     float* __restrict__ out) {
    const int id  = blockIdx.x * 256 + threadIdx.x;
    const int n   = id >> 12;
    const int pix = id & 4095;
    unsigned long long best = ~0ull;
    #pragma unroll
    for (int sp = 0; sp < SPLITS_V; ++sp) {
        unsigned long long v = partial[(sp * N_ + n) * HW_ + pix];
        best = v < best ? v : best;
    }
    const unsigned j = (unsigned)(best & 0xffffffffu);
    const float d2 = __uint_as_float((unsigned)(best >> 32));
    out[n * 2 * HW_ + pix]            = (float)(j >> 6);
    out[n * 2 * HW_ + HW_ + pix]      = (float)(j & 63);
    out[N_ * 2 * HW_ + n * HW_ + pix] = d2;
}

__global__ __launch_bounds__(256)
void patchmatch_mono_kernel(const float* __restrict__ s,
                            const float* __restrict__ t,
                            float* __restrict__ out) {
    const int yq  = blockIdx.x;
    const int n   = blockIdx.y;
    const int tid = threadIdx.x;
    const int tx  = tid & 15;
    const int ty  = tid >> 4;
    const int i0  = ty * 4;
    const int jrow = tx >> 3;
    const int jx0  = (tx & 7) * 8;

    __shared__ float qS[C_][3][68];
    __shared__ float tS[C_][4][68];
    __shared__ float pnS[HW_];
    __shared__ float qnS[W_];

    const float* sb = s + n * (C_ * HW_);
    const float* tb = t + n * (C_ * HW_);

    for (int jj = tid; jj < HW_; jj += 256) {
        const int y = jj >> 6, x = jj & 63;
        float acc = 0.f;
        for (int c = 0; c < C_; ++c) {
            const float* tc = tb + c * HW_;
            #pragma unroll
            for (int dy = 0; dy < 3; ++dy) {
                const float* tr = tc + iclamp(y + dy - 1, 0, H_ - 1) * W_;
                #pragma unroll
                for (int dx = 0; dx < 3; ++dx) {
                    float v = tr[iclamp(x + dx - 1, 0, W_ - 1)];
                    acc += v * v;
                }
            }
        }
        pnS[jj] = acc;
    }
    for (int idx = tid; idx < C_ * 3 * 66; idx += 256) {
        const int c   = idx / (3 * 66);
        const int rem = idx - c * (3 * 66);
        const int rr  = rem / 66;
        const int xi  = rem - rr * 66;
        qS[c][rr][xi] = sb[c * HW_ + iclamp(yq + rr - 1, 0, H_ - 1) * W_ +
                           iclamp(xi - 1, 0, W_ - 1)];
    }
    __syncthreads();
    if (tid < W_) {
        float acc = 0.f;
        for (int c = 0; c < C_; ++c)
            #pragma unroll
            for (int dy = 0; dy < 3; ++dy)
                #pragma unroll
                for (int dx = 0; dx < 3; ++dx) {
                    float v = qS[c][dy][tid + dx];
                    acc += v * v;
                }
        qnS[tid] = acc;
    }

    unsigned long long best[4] = {~0ull, ~0ull, ~0ull, ~0ull};
    for (int yt = 0; yt < 32; ++yt) {
        __syncthreads();
        for (int idx = tid; idx < C_ * 4 * 66; idx += 256) {
            const int c   = idx / (4 * 66);
            const int rem = idx - c * (4 * 66);
            const int rr  = rem / 66;
            const int xi  = rem - rr * 66;
            tS[c][rr][xi] = tb[c * HW_ + iclamp(2 * yt + rr - 1, 0, H_ - 1) * W_ +
                               iclamp(xi - 1, 0, W_ - 1)];
        }
        __syncthreads();

        float acc[4][8];
        #pragma unroll
        for (int a = 0; a < 4; ++a)
            #pragma unroll
            for (int b = 0; b < 8; ++b) acc[a][b] = 0.f;

        for (int c = 0; c < C_; ++c) {
            #pragma unroll
            for (int dy = 0; dy < 3; ++dy) {
                float qv[8], tv[12];
                *(float4*)&qv[0] = *(const float4*)&qS[c][dy][i0];
                *(float4*)&qv[4] = *(const float4*)&qS[c][dy][i0 + 4];
                const float* trow = &tS[c][jrow + dy][jx0];
                *(float4*)&tv[0] = *(const float4*)&trow[0];
                *(float4*)&tv[4] = *(const float4*)&trow[4];
                *(float4*)&tv[8] = *(const float4*)&trow[8];
                #pragma unroll
                for (int dx = 0; dx < 3; ++dx)
                    #pragma unroll
                    for (int a = 0; a < 4; ++a)
                        #pragma unroll
                        for (int b = 0; b < 8; ++b)
                            acc[a][b] += qv[a + dx] * tv[b + dx];
            }
        }
        const int rbase = (2 * yt + jrow) * W_ + jx0;
        #pragma unroll
        for (int a = 0; a < 4; ++a) {
            const float qn = qnS[i0 + a];
            #pragma unroll
            for (int b = 0; b < 8; ++b) {
                const int j = rbase + b;
                const float d2 = qn + pnS[j] - 2.f * acc[a][b];
                unsigned long long cand =
                    ((unsigned long long)__float_as_uint(d2) << 32) | (unsigned)j;
                best[a] = cand < best[a] ? cand : best[a];
            }
        }
    }
    #pragma unroll
    for (int a = 0; a < 4; ++a) {
        unsigned long long v = best[a];
        #pragma unroll
        for (int mm = 8; mm >= 1; mm >>= 1) {
            unsigned long long o = __shfl_xor(v, mm, 64);
            v = o < v ? o : v;
        }
        best[a] = v;
    }
    if (tx == 0) {
        #pragma unroll
        for (int a = 0; a < 4; ++a) {
            const int x = i0 + a;
            const unsigned j = (unsigned)(best[a] & 0xffffffffu);
            const float d2 = __uint_as_float((unsigned)(best[a] >> 32));
            const int pix = yq * W_ + x;
            out[n * 2 * HW_ + pix]            = (float)(j >> 6);
            out[n * 2 * HW_ + HW_ + pix]      = (float)(j & 63);
            out[N_ * 2 * HW_ + n * HW_ + pix] = d2;
        }
    }
}

// ===========================================================================
extern "C" void kernel_launch(void* const* d_in, const int* in_sizes, int n_in,
                              void* d_out, int out_size, void* d_ws, size_t ws_size,
                              hipStream_t stream) {
    const float* s = (const float*)d_in[0];
    const float* t = (const float*)d_in[1];
    float* out = (float*)d_out;

    // MFMA ws layout:
    //   pn [4][4096] f32 | qn [4][4096] f32 | partial [4][4][4096] u64 |
    //   Qh | Ql | Ph | Pl   each K-major [4][20][4096][8] f16 (5.24 MB)
    const size_t norm_b  = (size_t)N_ * HW_ * 4;
    const size_t part_b  = (size_t)SPLITS_M * N_ * HW_ * 8;
    const size_t desc_b  = (size_t)N_ * HW_ * K_ * 2;
    const size_t need_m  = 2 * norm_b + part_b + 4 * desc_b;     // ~21.5 MB

    if (ws_size >= need_m) {
        char* w = (char*)d_ws;
        float* pn = (float*)w;                       w += norm_b;
        float* qn = (float*)w;                       w += norm_b;
        unsigned long long* partial = (unsigned long long*)w; w += part_b;
        f16* Qh = (f16*)w;  w += desc_b;
        f16* Ql = (f16*)w;  w += desc_b;
        f16* Ph = (f16*)w;  w += desc_b;
        f16* Pl = (f16*)w;

        build_desc_norms_kernel<<<dim3(64, N_, 2), 256, 0, stream>>>(
            s, t, Qh, Ql, Ph, Pl, pn, qn);
        mfma_nn_kernel<<<512, 256, 0, stream>>>(Qh, Ql, Ph, Pl, pn, partial);
        finalize_mfma_kernel<<<64, 256, 0, stream>>>(partial, qn, out);
        return;
    }

    // Fallback: fp32 vector path
    const size_t need_v = 2 * norm_b + (size_t)SPLITS_V * N_ * HW_ * 8;
    if (ws_size >= need_v) {
        float* pn = (float*)d_ws;
        float* qn = pn + N_ * HW_;
        unsigned long long* partial =
            (unsigned long long*)((char*)d_ws + 2 * norm_b);
        prep_norms_kernel<<<128, 256, 0, stream>>>(s, t, pn, qn);
        dim3 grid(H_, N_, SPLITS_V);
        patchmatch_main_kernel<<<grid, 256, 0, stream>>>(s, t, pn, qn, partial);
        finalize_kernel<<<64, 256, 0, stream>>>(partial, out);
        return;
    }

    dim3 grid(H_, N_);
    patchmatch_mono_kernel<<<grid, 256, 0, stream>>>(s, t, out);
}